// Round 1
// baseline (382.415 us; speedup 1.0000x reference)
//
#include <hip/hip_runtime.h>

#define BB 256
#define LL 2048
#define HH 64
#define TT 128           // chunk length along L (8 waves x 16 t-steps)
#define SS 68            // padded LDS row stride (floats)
#define NCH (LL / TT)    // 16 chunks
#define NTOT (BB * LL * 2)

typedef __attribute__((ext_vector_type(8))) short bf16x8;
typedef __attribute__((ext_vector_type(4))) float f32x4;

__device__ __forceinline__ float rcp_(float x) { return __builtin_amdgcn_rcpf(x); }

// RNE fp32->bf16 (weights only, outside hot loop)
__device__ __forceinline__ short f2bf_rne(float f) {
    union { float f; unsigned u; } v; v.f = f;
    unsigned r = v.u + 0x7fff + ((v.u >> 16) & 1);
    return (short)(r >> 16);
}

// DPP row_shr:D with zero bound: lane i receives lane i-D within its 16-lane row
// (0 shifted in). Guarded uses only.
template<int D>
__device__ __forceinline__ float rshr(float x) {
    union { float f; int i; } u, r;
    u.f = x;
    r.i = __builtin_amdgcn_update_dpp(0, u.i, 0x110 | D, 0xF, 0xF, true);
    return r.f;
}

// Layer-0 gates (Bernoulli bit-LUT) + 128-step chunk scan:
// 16 local steps per thread, 8 segments per h, scanned via guarded row_shr DPP
// (receive-lane shares h iff seg >= stride). Writes h0 to sh with the 2-bit
// column swizzle so the 8 writer segments alias only 2-way on LDS banks.
__device__ __forceinline__ void p1_scan(const unsigned* __restrict__ bw, int c,
                                        float a0v, float b0v, float a1v, float b1v,
                                        int seg, int col0, int lane7,
                                        float& carry, float* sh)
{
    const unsigned bits = (bw[c * 4 + (seg >> 1)] >> ((seg & 1) << 4)) & 0xffffu;
    float ai[16], bi[16];
    float A = 1.0f, Bv = 0.0f;
    #pragma unroll
    for (int i = 0; i < 16; ++i) {
        const bool on = (bits >> i) & 1u;
        ai[i] = on ? a1v : a0v;
        bi[i] = on ? b1v : b0v;
        A  = A * ai[i];
        Bv = fmaf(Bv, ai[i], bi[i]);
    }
    // inclusive Hillis-Steele over 8 segments (strides 1,2,4)
    {
        const float Au = rshr<1>(A), Bu = rshr<1>(Bv);
        if (seg >= 1) { const float Ac = A; A = Au * Ac; Bv = fmaf(Bu, Ac, Bv); }
    }
    {
        const float Au = rshr<2>(A), Bu = rshr<2>(Bv);
        if (seg >= 2) { const float Ac = A; A = Au * Ac; Bv = fmaf(Bu, Ac, Bv); }
    }
    {
        const float Au = rshr<4>(A), Bu = rshr<4>(Bv);
        if (seg >= 4) { const float Ac = A; A = Au * Ac; Bv = fmaf(Bu, Ac, Bv); }
    }
    // exclusive transform for this segment's incoming state
    float Ae = rshr<1>(A), Be = rshr<1>(Bv);
    if (seg == 0) { Ae = 1.0f; Be = 0.0f; }
    float cc = fmaf(Ae, carry, Be);
    #pragma unroll
    for (int i = 0; i < 16; ++i) {
        cc = fmaf(ai[i], cc, bi[i]);
        sh[(seg * 16 + i) * SS + col0] = cc;
    }
    carry = __shfl(cc, lane7);   // seg==7 lane of this h-group holds chunk-final state
}

__global__ void __launch_bounds__(512)
__attribute__((amdgpu_waves_per_eu(4, 4)))   // 4 waves/EU -> 128 VGPR; 2 blocks/CU (LDS 78.1KB)
gru_fused(const float* __restrict__ x, const int* __restrict__ p,
               const float* __restrict__ w1z0, const float* __restrict__ b1z0,
               const float* __restrict__ w1h0, const float* __restrict__ b1h0,
               const float* __restrict__ w1z1, const float* __restrict__ b1z1,
               const float* __restrict__ w1h1, const float* __restrict__ b1h1,
               const float* __restrict__ w1o,  const float* __restrict__ b1o,
               const float* __restrict__ w2z0, const float* __restrict__ b2z0,
               const float* __restrict__ w2h0, const float* __restrict__ b2h0,
               const float* __restrict__ w2z1, const float* __restrict__ b2z1,
               const float* __restrict__ w2h1, const float* __restrict__ b2h1,
               const float* __restrict__ w2o,  const float* __restrict__ b2o,
               float* __restrict__ out, float* __restrict__ ws)
{
    const int  b  = blockIdx.x;
    const bool pm = (blockIdx.y != 0);

    const float* wz0 = pm ? w2z0 : w1z0;
    const float* bz0 = pm ? b2z0 : b1z0;
    const float* wh0 = pm ? w2h0 : w1h0;
    const float* bh0 = pm ? b2h0 : b1h0;
    const float* wz1 = pm ? w2z1 : w1z1;
    const float* bz1 = pm ? b2z1 : b1z1;
    const float* wh1 = pm ? w2h1 : w1h1;
    const float* bh1 = pm ? b2h1 : b1h1;
    const float* wo  = pm ? w2o  : w1o;
    const float* bov = pm ? b2o  : b1o;

    const int tid   = threadIdx.x;
    const int lane  = tid & 63;
    const int tg    = tid >> 6;          // wave id (8); owns t-block [16*tg, 16*tg+16)
    const int q     = lane >> 4;         // MFMA quad (t sub-block)
    const int n     = lane & 15;         // MFMA col (h low bits)
    const int seg   = lane & 7;          // P1 segment (8 per h)
    const int hidx  = (tg << 3) | (lane >> 3);   // P1 h channel
    const int lane7 = lane | 7;

    __shared__ __align__(16) float s_h[2 * TT * SS];        // double-buffered h0 (69.6 KB)
    __shared__ unsigned long long s_xb[LL / 64];            // bit-packed (permuted) x row
    __shared__ float2 s_w[2][8][HH];                        // per-wave scan transforms (A,B)
    __shared__ float s_red[16];

    const float* xrow = x + (size_t)b * LL;

    // ---- stage x row as BITS (ballot-packed; pm branch gathers once here) ----
    #pragma unroll
    for (int g = 0; g < 4; ++g) {
        const int idx = tg * 256 + g * 64 + lane;
        const int src = pm ? p[idx] : idx;
        const unsigned long long m = __ballot(xrow[src] != 0.0f);
        if (lane == 0) s_xb[tg * 4 + g] = m;
    }
    const unsigned* bw = (const unsigned*)s_xb;

    // ---- layer-0 LUT per hidx (x is bernoulli {0,1}) ----
    const float z0v = rcp_(1.0f + __expf(-bz0[hidx]));
    const float z1v = rcp_(1.0f + __expf(-(wz0[hidx] + bz0[hidx])));
    const float a0v = 1.0f - z0v, b0v = z0v * bh0[hidx];
    const float a1v = 1.0f - z1v, b1v = z1v * (wh0[hidx] + bh0[hidx]);

    // ---- layer-1 biases + output weights (MFMA (ht,n) mapping) ----
    float rbz1[4], rbh1[4], rwo4[4];
    #pragma unroll
    for (int ht = 0; ht < 4; ++ht) {
        rbz1[ht] = bz1[ht * 16 + n];
        rbh1[ht] = bh1[ht * 16 + n];
        rwo4[ht] = wo[ht * 16 + n];
    }
    const float bo = bov[0];

    // ---- layer-1 weight B-fragments, RNE hi only ----
    bf16x8 wfz[2][4], wfh[2][4];
    for (int ks = 0; ks < 2; ++ks) {
        for (int ht = 0; ht < 4; ++ht) {
            #pragma unroll
            for (int j = 0; j < 8; ++j) {
                const int kk = ks * 32 + q * 8 + j;
                const int hh = ht * 16 + n;
                wfz[ks][ht][j] = f2bf_rne(wz1[kk * HH + hh]);
                wfh[ks][ht][j] = f2bf_rne(wh1[kk * HH + hh]);
            }
        }
    }

    float carry0 = 0.0f;
    float carry1[4] = {0.0f, 0.0f, 0.0f, 0.0f};   // per ht (h = ht*16+n)
    f32x4 ga[4], gb[4];                            // layer-1 gates (a,b), chunk-persistent
    float Aqe[4], Bqe[4];                          // exclusive-q transforms, chunk-persistent
    float lsum = 0.0f, lsum2 = 0.0f;
    float* outp = out + (pm ? 1 : 0);
    const int t0 = tg * 16;
    // s_h col swizzle (write side): 2 bits so 8 segs alias only 2-way per bank
    const int col0 = hidx ^ ((seg & 1) << 4) ^ ((seg & 2) << 2);

    // G2: apply layer-1 scan for chunk cm (gates/Aqe of cm live in registers),
    // fused output projection (DPP shift-reduce over n) + store.
    auto g2_step = [&](int cm) {
        const int buf = cm & 1;
        float Acm[4] = {1,1,1,1}, Bcm[4] = {0,0,0,0};
        float Ap[4], Bp[4];
        #pragma unroll
        for (int w = 0; w < 8; ++w) {
            #pragma unroll
            for (int ht = 0; ht < 4; ++ht) {
                if (w == tg) { Ap[ht] = Acm[ht]; Bp[ht] = Bcm[ht]; }
                const float2 ab = s_w[buf][w][ht * 16 + n];
                Bcm[ht] = fmaf(ab.x, Bcm[ht], ab.y);
                Acm[ht] *= ab.x;
            }
        }
        float vo[4] = {0,0,0,0};
        #pragma unroll
        for (int ht = 0; ht < 4; ++ht) {
            float cc = fmaf(Aqe[ht], fmaf(Ap[ht], carry1[ht], Bp[ht]), Bqe[ht]);
            #pragma unroll
            for (int r = 0; r < 4; ++r) {
                cc = fmaf(ga[ht][r], cc, gb[ht][r]);
                vo[r] = fmaf(cc, rwo4[ht], vo[r]);
            }
            carry1[ht] = fmaf(Acm[ht], carry1[ht], Bcm[ht]);
        }
        // shift-reduce over n (16-lane rows) on the VALU: lane n==15 gets the sum
        #pragma unroll
        for (int r = 0; r < 4; ++r) {
            vo[r] += rshr<1>(vo[r]);
            vo[r] += rshr<2>(vo[r]);
            vo[r] += rshr<4>(vo[r]);
            vo[r] += rshr<8>(vo[r]);
        }
        if (n == 15) {
            #pragma unroll
            for (int r = 0; r < 4; ++r) {
                const float v = vo[r] + bo;
                outp[((size_t)b * LL + cm * TT + t0 + q * 4 + r) * 2] = v;
                lsum += v;
                lsum2 = fmaf(v, v, lsum2);
            }
        }
    };

    __syncthreads();   // s_xb staged

    // ---- prologue: P1(0) -> s_h buf 0 ----
    p1_scan(bw, 0, a0v, b0v, a1v, b1v, seg, col0, lane7, carry0, s_h);
    __syncthreads();

    for (int c = 0; c < NCH; ++c) {
        const int cp1 = c + 1;

        // ---- G2(c-1): uses previous chunk's gates (still in registers) ----
        if (c > 0) g2_step(c - 1);

        // ---- G1(c): MFMA + gates + per-wave scan transforms ----
        {
            #pragma unroll
            for (int ht = 0; ht < 4; ++ht) {
                ga[ht] = (f32x4){rbz1[ht], rbz1[ht], rbz1[ht], rbz1[ht]};
                gb[ht] = (f32x4){rbh1[ht], rbh1[ht], rbh1[ht], rbh1[ht]};
            }
            const float* shR = s_h + (c & 1) * (TT * SS);
            // undo s_h col swizzle: writer seg == row>>4 == tg for this wave's rows
            const int qs = q ^ (((tg & 1) << 1) | ((tg >> 1) & 1));
            #pragma unroll
            for (int ks = 0; ks < 2; ++ks) {
                const float* ap = &shR[(t0 + n) * SS + ks * 32 + qs * 8];
                const float4 av0 = *(const float4*)ap;
                const float4 av1 = *(const float4*)(ap + 4);
                float af[8] = {av0.x, av0.y, av0.z, av0.w, av1.x, av1.y, av1.z, av1.w};
                bf16x8 ahi, alo;
                #pragma unroll
                for (int j = 0; j < 8; ++j) {
                    union { float f; unsigned u; } uf; uf.f = af[j];
                    ahi[j] = (short)(uf.u >> 16);                       // truncate
                    union { unsigned u; float f; } hf; hf.u = uf.u & 0xffff0000u;
                    const float rem = af[j] - hf.f;                     // exact
                    union { float f; unsigned u; } ur; ur.f = rem;
                    alo[j] = (short)(ur.u >> 16);
                }
                #pragma unroll
                for (int ht = 0; ht < 4; ++ht) {
                    ga[ht] = __builtin_amdgcn_mfma_f32_16x16x32_bf16(ahi, wfz[ks][ht], ga[ht], 0, 0, 0);
                    ga[ht] = __builtin_amdgcn_mfma_f32_16x16x32_bf16(alo, wfz[ks][ht], ga[ht], 0, 0, 0);
                    gb[ht] = __builtin_amdgcn_mfma_f32_16x16x32_bf16(ahi, wfh[ks][ht], gb[ht], 0, 0, 0);
                    gb[ht] = __builtin_amdgcn_mfma_f32_16x16x32_bf16(alo, wfh[ks][ht], gb[ht], 0, 0, 0);
                }
            }
            // gates in place: a = 1-sigmoid(v) = rcp(1+exp(v)); b = htl - a*htl
            #pragma unroll
            for (int ht = 0; ht < 4; ++ht) {
                #pragma unroll
                for (int r = 0; r < 4; ++r) {
                    const float v   = ga[ht][r];
                    const float a   = rcp_(1.0f + __expf(v));
                    const float htl = gb[ht][r];
                    ga[ht][r] = a;
                    gb[ht][r] = fmaf(-a, htl, htl);
                }
            }
            // compose own 4 r-steps per ht
            float Aq[4], Bq[4];
            #pragma unroll
            for (int ht = 0; ht < 4; ++ht) {
                float A = 1.0f, B = 0.0f;
                #pragma unroll
                for (int r = 0; r < 4; ++r) {
                    B = fmaf(ga[ht][r], B, gb[ht][r]);
                    A = A * ga[ht][r];
                }
                Aq[ht] = A; Bq[ht] = B;
            }
            // inclusive Hillis-Steele over q (strides 16, 32 lanes)
            #pragma unroll
            for (int ht = 0; ht < 4; ++ht) {
                const float Au = __shfl_up(Aq[ht], 16), Bu = __shfl_up(Bq[ht], 16);
                if (q >= 1) { const float Ac = Aq[ht]; Aq[ht] = Ac * Au; Bq[ht] = fmaf(Ac, Bu, Bq[ht]); }
            }
            #pragma unroll
            for (int ht = 0; ht < 4; ++ht) {
                const float Au = __shfl_up(Aq[ht], 32), Bu = __shfl_up(Bq[ht], 32);
                if (q >= 2) { const float Ac = Aq[ht]; Aq[ht] = Ac * Au; Bq[ht] = fmaf(Ac, Bu, Bq[ht]); }
            }
            // exclusive-q transforms (persist to G2)
            #pragma unroll
            for (int ht = 0; ht < 4; ++ht) {
                const float Ae = __shfl_up(Aq[ht], 16), Be = __shfl_up(Bq[ht], 16);
                Aqe[ht] = (q == 0) ? 1.0f : Ae;
                Bqe[ht] = (q == 0) ? 0.0f : Be;
            }
            // q==3 lanes publish the wave-block inclusive transform
            if (q == 3) {
                #pragma unroll
                for (int ht = 0; ht < 4; ++ht)
                    s_w[c & 1][tg][ht * 16 + n] = make_float2(Aq[ht], Bq[ht]);
            }
        }

        // ---- P1(c+1) -> other s_h buffer (reads bit-packed x) ----
        if (cp1 < NCH)
            p1_scan(bw, cp1, a0v, b0v, a1v, b1v, seg, col0, lane7, carry0,
                    s_h + (cp1 & 1) * (TT * SS));

        __syncthreads();
    }

    // ---- G2 for the last chunk ----
    g2_step(NCH - 1);

    // ---- block partial (sum, sumsq) -> ws slots (plain stores) ----
    #pragma unroll
    for (int o = 32; o; o >>= 1) {
        lsum  += __shfl_down(lsum, o);
        lsum2 += __shfl_down(lsum2, o);
    }
    if (lane == 0) { s_red[tg] = lsum; s_red[8 + tg] = lsum2; }
    __syncthreads();
    if (tid == 0) {
        float s = 0.0f, s2 = 0.0f;
        #pragma unroll
        for (int i = 0; i < 8; ++i) { s += s_red[i]; s2 += s_red[8 + i]; }
        const int gb2 = b * 2 + (pm ? 1 : 0);
        ws[2 * gb2]     = s;
        ws[2 * gb2 + 1] = s2;
    }
}

// Fold the 512 block-partials (redundantly per block), normalize in-place.
__global__ void normalize_k(float* __restrict__ out, const float* __restrict__ ws)
{
    __shared__ float s_red[8];
    float s = 0.0f, s2 = 0.0f;
    for (int i = threadIdx.x; i < 2 * BB; i += 256) {
        s  += ws[2 * i];
        s2 += ws[2 * i + 1];
    }
    #pragma unroll
    for (int o = 32; o; o >>= 1) {
        s  += __shfl_down(s, o);
        s2 += __shfl_down(s2, o);
    }
    const int wid = threadIdx.x >> 6;
    if ((threadIdx.x & 63) == 0) { s_red[wid] = s; s_red[4 + wid] = s2; }
    __syncthreads();
    const float tot  = s_red[0] + s_red[1] + s_red[2] + s_red[3];
    const float tot2 = s_red[4] + s_red[5] + s_red[6] + s_red[7];
    const float N    = (float)NTOT;
    const float mean = tot / N;
    const float var  = (tot2 - N * mean * mean) / (N - 1.0f);
    const float inv  = rsqrtf(var);

    const int i = blockIdx.x * blockDim.x + threadIdx.x;   // exactly NTOT/4 threads
    float4* o4 = (float4*)out;
    float4 v = o4[i];
    v.x = (v.x - mean) * inv;
    v.y = (v.y - mean) * inv;
    v.z = (v.z - mean) * inv;
    v.w = (v.w - mean) * inv;
    o4[i] = v;
}

extern "C" void kernel_launch(void* const* d_in, const int* in_sizes, int n_in,
                              void* d_out, int out_size, void* d_ws, size_t ws_size,
                              hipStream_t stream)
{
    (void)in_sizes; (void)n_in; (void)out_size; (void)ws_size;
    const float* x = (const float*)d_in[0];
    const int*   p = (const int*)d_in[1];
    float* out = (float*)d_out;
    float* ws  = (float*)d_ws;

    dim3 grid(BB, 2);
    gru_fused<<<grid, 512, 0, stream>>>(
        x, p,
        (const float*)d_in[2],  (const float*)d_in[3],
        (const float*)d_in[4],  (const float*)d_in[5],
        (const float*)d_in[6],  (const float*)d_in[7],
        (const float*)d_in[8],  (const float*)d_in[9],
        (const float*)d_in[10], (const float*)d_in[11],
        (const float*)d_in[12], (const float*)d_in[13],
        (const float*)d_in[14], (const float*)d_in[15],
        (const float*)d_in[16], (const float*)d_in[17],
        (const float*)d_in[18], (const float*)d_in[19],
        (const float*)d_in[20], (const float*)d_in[21],
        out, ws);

    normalize_k<<<NTOT / 4 / 256, 256, 0, stream>>>(out, ws);
}

// Round 2
// 382.357 us; speedup vs baseline: 1.0002x; 1.0002x over previous
//
#include <hip/hip_runtime.h>

#define BB 256
#define LL 2048
#define HH 64
#define TT 128           // chunk length along L (8 waves x 16 t-steps)
#define SS 68            // padded LDS row stride (floats)
#define NCH (LL / TT)    // 16 chunks
#define NTOT (BB * LL * 2)

typedef __attribute__((ext_vector_type(8))) short bf16x8;
typedef __attribute__((ext_vector_type(4))) float f32x4;

__device__ __forceinline__ float rcp_(float x) { return __builtin_amdgcn_rcpf(x); }

// RNE fp32->bf16 (weights only, outside hot loop)
__device__ __forceinline__ short f2bf_rne(float f) {
    union { float f; unsigned u; } v; v.f = f;
    unsigned r = v.u + 0x7fff + ((v.u >> 16) & 1);
    return (short)(r >> 16);
}

// DPP row_shr:D with zero bound: lane i receives lane i-D within its 16-lane row
// (0 shifted in). Guarded uses only.
template<int D>
__device__ __forceinline__ float rshr(float x) {
    union { float f; int i; } u, r;
    u.f = x;
    r.i = __builtin_amdgcn_update_dpp(0, u.i, 0x110 | D, 0xF, 0xF, true);
    return r.f;
}

// Layer-0 gates (Bernoulli bit-LUT) + 128-step chunk scan:
// 16 local steps per thread, 8 segments per h, scanned via guarded row_shr DPP
// (receive-lane shares h iff seg >= stride). Writes h0 to sh with the 2-bit
// column swizzle so the 8 writer segments alias only 2-way on LDS banks.
// NOTE: the per-step (a,b) gate pair is RECOMPUTED from the packed bits in the
// apply loop instead of cached in ai[16]/bi[16] — saves ~32 live VGPRs across
// the DPP scan, which is what made the 128-reg budget spill in the last rev.
__device__ __forceinline__ void p1_scan(const unsigned* __restrict__ bw, int c,
                                        float a0v, float b0v, float a1v, float b1v,
                                        int seg, int col0, int lane7,
                                        float& carry, float* sh)
{
    const unsigned bits = (bw[c * 4 + (seg >> 1)] >> ((seg & 1) << 4)) & 0xffffu;
    float A = 1.0f, Bv = 0.0f;
    #pragma unroll
    for (int i = 0; i < 16; ++i) {
        const bool on = (bits >> i) & 1u;
        const float a = on ? a1v : a0v;
        const float b = on ? b1v : b0v;
        A  = A * a;
        Bv = fmaf(Bv, a, b);
    }
    // inclusive Hillis-Steele over 8 segments (strides 1,2,4)
    {
        const float Au = rshr<1>(A), Bu = rshr<1>(Bv);
        if (seg >= 1) { const float Ac = A; A = Au * Ac; Bv = fmaf(Bu, Ac, Bv); }
    }
    {
        const float Au = rshr<2>(A), Bu = rshr<2>(Bv);
        if (seg >= 2) { const float Ac = A; A = Au * Ac; Bv = fmaf(Bu, Ac, Bv); }
    }
    {
        const float Au = rshr<4>(A), Bu = rshr<4>(Bv);
        if (seg >= 4) { const float Ac = A; A = Au * Ac; Bv = fmaf(Bu, Ac, Bv); }
    }
    // exclusive transform for this segment's incoming state
    float Ae = rshr<1>(A), Be = rshr<1>(Bv);
    if (seg == 0) { Ae = 1.0f; Be = 0.0f; }
    float cc = fmaf(Ae, carry, Be);
    #pragma unroll
    for (int i = 0; i < 16; ++i) {
        const bool on = (bits >> i) & 1u;
        const float a = on ? a1v : a0v;
        const float b = on ? b1v : b0v;
        cc = fmaf(a, cc, b);
        sh[(seg * 16 + i) * SS + col0] = cc;
    }
    carry = __shfl(cc, lane7);   // seg==7 lane of this h-group holds chunk-final state
}

__global__ void __launch_bounds__(512)
__attribute__((amdgpu_waves_per_eu(4, 4)))   // 4 waves/EU: 128-reg budget; demand now fits
gru_fused(const float* __restrict__ x, const int* __restrict__ p,
               const float* __restrict__ w1z0, const float* __restrict__ b1z0,
               const float* __restrict__ w1h0, const float* __restrict__ b1h0,
               const float* __restrict__ w1z1, const float* __restrict__ b1z1,
               const float* __restrict__ w1h1, const float* __restrict__ b1h1,
               const float* __restrict__ w1o,  const float* __restrict__ b1o,
               const float* __restrict__ w2z0, const float* __restrict__ b2z0,
               const float* __restrict__ w2h0, const float* __restrict__ b2h0,
               const float* __restrict__ w2z1, const float* __restrict__ b2z1,
               const float* __restrict__ w2h1, const float* __restrict__ b2h1,
               const float* __restrict__ w2o,  const float* __restrict__ b2o,
               float* __restrict__ out, float* __restrict__ ws)
{
    const int  b  = blockIdx.x;
    const bool pm = (blockIdx.y != 0);

    const float* wz0 = pm ? w2z0 : w1z0;
    const float* bz0 = pm ? b2z0 : b1z0;
    const float* wh0 = pm ? w2h0 : w1h0;
    const float* bh0 = pm ? b2h0 : b1h0;
    const float* wz1 = pm ? w2z1 : w1z1;
    const float* bz1 = pm ? b2z1 : b1z1;
    const float* wh1 = pm ? w2h1 : w1h1;
    const float* bh1 = pm ? b2h1 : b1h1;
    const float* wo  = pm ? w2o  : w1o;
    const float* bov = pm ? b2o  : b1o;

    const int tid   = threadIdx.x;
    const int lane  = tid & 63;
    const int tg    = tid >> 6;          // wave id (8); owns t-block [16*tg, 16*tg+16)
    const int q     = lane >> 4;         // MFMA quad (t sub-block)
    const int n     = lane & 15;         // MFMA col (h low bits)
    const int seg   = lane & 7;          // P1 segment (8 per h)
    const int hidx  = (tg << 3) | (lane >> 3);   // P1 h channel
    const int lane7 = lane | 7;

    __shared__ __align__(16) float s_h[2 * TT * SS];        // double-buffered h0 (69.6 KB)
    __shared__ unsigned long long s_xb[LL / 64];            // bit-packed (permuted) x row
    __shared__ float2 s_w[2][8][HH];                        // per-wave scan transforms (A,B)
    __shared__ float s_red[16];

    const float* xrow = x + (size_t)b * LL;

    // ---- stage x row as BITS (ballot-packed; pm branch gathers once here) ----
    #pragma unroll
    for (int g = 0; g < 4; ++g) {
        const int idx = tg * 256 + g * 64 + lane;
        const int src = pm ? p[idx] : idx;
        const unsigned long long m = __ballot(xrow[src] != 0.0f);
        if (lane == 0) s_xb[tg * 4 + g] = m;
    }
    const unsigned* bw = (const unsigned*)s_xb;

    // ---- layer-0 LUT per hidx (x is bernoulli {0,1}) ----
    const float z0v = rcp_(1.0f + __expf(-bz0[hidx]));
    const float z1v = rcp_(1.0f + __expf(-(wz0[hidx] + bz0[hidx])));
    const float a0v = 1.0f - z0v, b0v = z0v * bh0[hidx];
    const float a1v = 1.0f - z1v, b1v = z1v * (wh0[hidx] + bh0[hidx]);

    // ---- layer-1 biases + output weights (MFMA (ht,n) mapping) ----
    float rbz1[4], rbh1[4], rwo4[4];
    #pragma unroll
    for (int ht = 0; ht < 4; ++ht) {
        rbz1[ht] = bz1[ht * 16 + n];
        rbh1[ht] = bh1[ht * 16 + n];
        rwo4[ht] = wo[ht * 16 + n];
    }
    const float bo = bov[0];

    // ---- layer-1 weight B-fragments, RNE hi only ----
    bf16x8 wfz[2][4], wfh[2][4];
    for (int ks = 0; ks < 2; ++ks) {
        for (int ht = 0; ht < 4; ++ht) {
            #pragma unroll
            for (int j = 0; j < 8; ++j) {
                const int kk = ks * 32 + q * 8 + j;
                const int hh = ht * 16 + n;
                wfz[ks][ht][j] = f2bf_rne(wz1[kk * HH + hh]);
                wfh[ks][ht][j] = f2bf_rne(wh1[kk * HH + hh]);
            }
        }
    }

    float carry0 = 0.0f;
    float carry1[4] = {0.0f, 0.0f, 0.0f, 0.0f};   // per ht (h = ht*16+n)
    f32x4 ga[4], gb[4];                            // layer-1 gates (a,b), chunk-persistent
    float Aqe[4], Bqe[4];                          // exclusive-q transforms, chunk-persistent
    float lsum = 0.0f, lsum2 = 0.0f;
    float* outp = out + (pm ? 1 : 0);
    const int t0 = tg * 16;
    // s_h col swizzle (write side): 2 bits so 8 segs alias only 2-way per bank
    const int col0 = hidx ^ ((seg & 1) << 4) ^ ((seg & 2) << 2);

    // G2: apply layer-1 scan for chunk cm (gates/Aqe of cm live in registers),
    // fused output projection (DPP shift-reduce over n) + store.
    auto g2_step = [&](int cm) {
        const int buf = cm & 1;
        float Acm[4] = {1,1,1,1}, Bcm[4] = {0,0,0,0};
        float Ap[4], Bp[4];
        #pragma unroll
        for (int w = 0; w < 8; ++w) {
            #pragma unroll
            for (int ht = 0; ht < 4; ++ht) {
                if (w == tg) { Ap[ht] = Acm[ht]; Bp[ht] = Bcm[ht]; }
                const float2 ab = s_w[buf][w][ht * 16 + n];
                Bcm[ht] = fmaf(ab.x, Bcm[ht], ab.y);
                Acm[ht] *= ab.x;
            }
        }
        float vo[4] = {0,0,0,0};
        #pragma unroll
        for (int ht = 0; ht < 4; ++ht) {
            float cc = fmaf(Aqe[ht], fmaf(Ap[ht], carry1[ht], Bp[ht]), Bqe[ht]);
            #pragma unroll
            for (int r = 0; r < 4; ++r) {
                cc = fmaf(ga[ht][r], cc, gb[ht][r]);
                vo[r] = fmaf(cc, rwo4[ht], vo[r]);
            }
            carry1[ht] = fmaf(Acm[ht], carry1[ht], Bcm[ht]);
        }
        // shift-reduce over n (16-lane rows) on the VALU: lane n==15 gets the sum
        #pragma unroll
        for (int r = 0; r < 4; ++r) {
            vo[r] += rshr<1>(vo[r]);
            vo[r] += rshr<2>(vo[r]);
            vo[r] += rshr<4>(vo[r]);
            vo[r] += rshr<8>(vo[r]);
        }
        if (n == 15) {
            #pragma unroll
            for (int r = 0; r < 4; ++r) {
                const float v = vo[r] + bo;
                outp[((size_t)b * LL + cm * TT + t0 + q * 4 + r) * 2] = v;
                lsum += v;
                lsum2 = fmaf(v, v, lsum2);
            }
        }
    };

    __syncthreads();   // s_xb staged

    // ---- prologue: P1(0) -> s_h buf 0 ----
    p1_scan(bw, 0, a0v, b0v, a1v, b1v, seg, col0, lane7, carry0, s_h);
    __syncthreads();

    for (int c = 0; c < NCH; ++c) {
        const int cp1 = c + 1;

        // ---- G2(c-1): uses previous chunk's gates (still in registers) ----
        if (c > 0) g2_step(c - 1);

        // ---- G1(c): MFMA + gates + per-wave scan transforms ----
        {
            #pragma unroll
            for (int ht = 0; ht < 4; ++ht) {
                ga[ht] = (f32x4){rbz1[ht], rbz1[ht], rbz1[ht], rbz1[ht]};
                gb[ht] = (f32x4){rbh1[ht], rbh1[ht], rbh1[ht], rbh1[ht]};
            }
            const float* shR = s_h + (c & 1) * (TT * SS);
            // undo s_h col swizzle: writer seg == row>>4 == tg for this wave's rows
            const int qs = q ^ (((tg & 1) << 1) | ((tg >> 1) & 1));
            #pragma unroll
            for (int ks = 0; ks < 2; ++ks) {
                const float* ap = &shR[(t0 + n) * SS + ks * 32 + qs * 8];
                const float4 av0 = *(const float4*)ap;
                const float4 av1 = *(const float4*)(ap + 4);
                float af[8] = {av0.x, av0.y, av0.z, av0.w, av1.x, av1.y, av1.z, av1.w};
                bf16x8 ahi, alo;
                #pragma unroll
                for (int j = 0; j < 8; ++j) {
                    union { float f; unsigned u; } uf; uf.f = af[j];
                    ahi[j] = (short)(uf.u >> 16);                       // truncate
                    union { unsigned u; float f; } hf; hf.u = uf.u & 0xffff0000u;
                    const float rem = af[j] - hf.f;                     // exact
                    union { float f; unsigned u; } ur; ur.f = rem;
                    alo[j] = (short)(ur.u >> 16);
                }
                #pragma unroll
                for (int ht = 0; ht < 4; ++ht) {
                    ga[ht] = __builtin_amdgcn_mfma_f32_16x16x32_bf16(ahi, wfz[ks][ht], ga[ht], 0, 0, 0);
                    ga[ht] = __builtin_amdgcn_mfma_f32_16x16x32_bf16(alo, wfz[ks][ht], ga[ht], 0, 0, 0);
                    gb[ht] = __builtin_amdgcn_mfma_f32_16x16x32_bf16(ahi, wfh[ks][ht], gb[ht], 0, 0, 0);
                    gb[ht] = __builtin_amdgcn_mfma_f32_16x16x32_bf16(alo, wfh[ks][ht], gb[ht], 0, 0, 0);
                }
            }
            // gates in place: a = 1-sigmoid(v) = rcp(1+exp(v)); b = htl - a*htl
            #pragma unroll
            for (int ht = 0; ht < 4; ++ht) {
                #pragma unroll
                for (int r = 0; r < 4; ++r) {
                    const float v   = ga[ht][r];
                    const float a   = rcp_(1.0f + __expf(v));
                    const float htl = gb[ht][r];
                    ga[ht][r] = a;
                    gb[ht][r] = fmaf(-a, htl, htl);
                }
            }
            // compose own 4 r-steps per ht
            float Aq[4], Bq[4];
            #pragma unroll
            for (int ht = 0; ht < 4; ++ht) {
                float A = 1.0f, B = 0.0f;
                #pragma unroll
                for (int r = 0; r < 4; ++r) {
                    B = fmaf(ga[ht][r], B, gb[ht][r]);
                    A = A * ga[ht][r];
                }
                Aq[ht] = A; Bq[ht] = B;
            }
            // inclusive Hillis-Steele over q (strides 16, 32 lanes)
            #pragma unroll
            for (int ht = 0; ht < 4; ++ht) {
                const float Au = __shfl_up(Aq[ht], 16), Bu = __shfl_up(Bq[ht], 16);
                if (q >= 1) { const float Ac = Aq[ht]; Aq[ht] = Ac * Au; Bq[ht] = fmaf(Ac, Bu, Bq[ht]); }
            }
            #pragma unroll
            for (int ht = 0; ht < 4; ++ht) {
                const float Au = __shfl_up(Aq[ht], 32), Bu = __shfl_up(Bq[ht], 32);
                if (q >= 2) { const float Ac = Aq[ht]; Aq[ht] = Ac * Au; Bq[ht] = fmaf(Ac, Bu, Bq[ht]); }
            }
            // exclusive-q transforms (persist to G2)
            #pragma unroll
            for (int ht = 0; ht < 4; ++ht) {
                const float Ae = __shfl_up(Aq[ht], 16), Be = __shfl_up(Bq[ht], 16);
                Aqe[ht] = (q == 0) ? 1.0f : Ae;
                Bqe[ht] = (q == 0) ? 0.0f : Be;
            }
            // q==3 lanes publish the wave-block inclusive transform
            if (q == 3) {
                #pragma unroll
                for (int ht = 0; ht < 4; ++ht)
                    s_w[c & 1][tg][ht * 16 + n] = make_float2(Aq[ht], Bq[ht]);
            }
        }

        // ---- P1(c+1) -> other s_h buffer (reads bit-packed x) ----
        if (cp1 < NCH)
            p1_scan(bw, cp1, a0v, b0v, a1v, b1v, seg, col0, lane7, carry0,
                    s_h + (cp1 & 1) * (TT * SS));

        __syncthreads();
    }

    // ---- G2 for the last chunk ----
    g2_step(NCH - 1);

    // ---- block partial (sum, sumsq) -> ws slots (plain stores) ----
    #pragma unroll
    for (int o = 32; o; o >>= 1) {
        lsum  += __shfl_down(lsum, o);
        lsum2 += __shfl_down(lsum2, o);
    }
    if (lane == 0) { s_red[tg] = lsum; s_red[8 + tg] = lsum2; }
    __syncthreads();
    if (tid == 0) {
        float s = 0.0f, s2 = 0.0f;
        #pragma unroll
        for (int i = 0; i < 8; ++i) { s += s_red[i]; s2 += s_red[8 + i]; }
        const int gb2 = b * 2 + (pm ? 1 : 0);
        ws[2 * gb2]     = s;
        ws[2 * gb2 + 1] = s2;
    }
}

// Fold the 512 block-partials (redundantly per block), normalize in-place.
__global__ void normalize_k(float* __restrict__ out, const float* __restrict__ ws)
{
    __shared__ float s_red[8];
    float s = 0.0f, s2 = 0.0f;
    for (int i = threadIdx.x; i < 2 * BB; i += 256) {
        s  += ws[2 * i];
        s2 += ws[2 * i + 1];
    }
    #pragma unroll
    for (int o = 32; o; o >>= 1) {
        s  += __shfl_down(s, o);
        s2 += __shfl_down(s2, o);
    }
    const int wid = threadIdx.x >> 6;
    if ((threadIdx.x & 63) == 0) { s_red[wid] = s; s_red[4 + wid] = s2; }
    __syncthreads();
    const float tot  = s_red[0] + s_red[1] + s_red[2] + s_red[3];
    const float tot2 = s_red[4] + s_red[5] + s_red[6] + s_red[7];
    const float N    = (float)NTOT;
    const float mean = tot / N;
    const float var  = (tot2 - N * mean * mean) / (N - 1.0f);
    const float inv  = rsqrtf(var);

    const int i = blockIdx.x * blockDim.x + threadIdx.x;   // exactly NTOT/4 threads
    float4* o4 = (float4*)out;
    float4 v = o4[i];
    v.x = (v.x - mean) * inv;
    v.y = (v.y - mean) * inv;
    v.z = (v.z - mean) * inv;
    v.w = (v.w - mean) * inv;
    o4[i] = v;
}

extern "C" void kernel_launch(void* const* d_in, const int* in_sizes, int n_in,
                              void* d_out, int out_size, void* d_ws, size_t ws_size,
                              hipStream_t stream)
{
    (void)in_sizes; (void)n_in; (void)out_size; (void)ws_size;
    const float* x = (const float*)d_in[0];
    const int*   p = (const int*)d_in[1];
    float* out = (float*)d_out;
    float* ws  = (float*)d_ws;

    dim3 grid(BB, 2);
    gru_fused<<<grid, 512, 0, stream>>>(
        x, p,
        (const float*)d_in[2],  (const float*)d_in[3],
        (const float*)d_in[4],  (const float*)d_in[5],
        (const float*)d_in[6],  (const float*)d_in[7],
        (const float*)d_in[8],  (const float*)d_in[9],
        (const float*)d_in[10], (const float*)d_in[11],
        (const float*)d_in[12], (const float*)d_in[13],
        (const float*)d_in[14], (const float*)d_in[15],
        (const float*)d_in[16], (const float*)d_in[17],
        (const float*)d_in[18], (const float*)d_in[19],
        (const float*)d_in[20], (const float*)d_in[21],
        out, ws);

    normalize_k<<<NTOT / 4 / 256, 256, 0, stream>>>(out, ws);
}

// Round 3
// 281.179 us; speedup vs baseline: 1.3600x; 1.3598x over previous
//
#include <hip/hip_runtime.h>

#define BB 256
#define LL 2048
#define HH 64
#define TT 64            // chunk length along L
#define SS 68            // padded LDS row stride (floats)
#define NCH (LL / TT)    // 32 chunks
#define NTOT (BB * LL * 2)

typedef __attribute__((ext_vector_type(8))) short bf16x8;
typedef __attribute__((ext_vector_type(4))) float f32x4;

__device__ __forceinline__ float rcp_(float x) { return __builtin_amdgcn_rcpf(x); }

// RNE fp32->bf16 (weights only, outside hot loop)
__device__ __forceinline__ short f2bf_rne(float f) {
    union { float f; unsigned u; } v; v.f = f;
    unsigned r = v.u + 0x7fff + ((v.u >> 16) & 1);
    return (short)(r >> 16);
}

// DPP quad_perm: 0x90 = shift-up-1, 0x44 = shift-up-2, 0xFF = bcast lane3 of quad.
template<int CTRL>
__device__ __forceinline__ float qdpp(float x) {
    union { float f; int i; } u, r;
    u.f = x;
    r.i = __builtin_amdgcn_update_dpp(0, u.i, CTRL, 0xF, 0xF, false);
    return r.f;
}

// DPP row_shr:D with zero bound (used by G2's n-reduce).
template<int D>
__device__ __forceinline__ float rshr(float x) {
    union { float f; int i; } u, r;
    u.f = x;
    r.i = __builtin_amdgcn_update_dpp(0, u.i, 0x110 | D, 0xF, 0xF, true);
    return r.f;
}

// Layer-0 gates (Bernoulli bit-LUT) + 64-step chunk scan (16 local + quad scan
// via DPP). Gates are RECOMPUTED from the packed bits in the apply loop instead
// of cached in xi/ai/bi arrays — removes the ~48-VGPR peak of the round-0 rev.
__device__ __forceinline__ void p1_scan(const unsigned* __restrict__ bw, int c,
                                        float a0v, float b0v, float a1v, float b1v,
                                        int seg, int col0, float& carry, float* sh)
{
    const unsigned bits = (bw[c * 2 + (seg >> 1)] >> ((seg & 1) << 4)) & 0xffffu;
    float A = 1.0f, Bv = 0.0f;
    #pragma unroll
    for (int i = 0; i < 16; ++i) {
        const bool on = (bits >> i) & 1u;
        const float a = on ? a1v : a0v;
        const float b = on ? b1v : b0v;
        A  = A * a;
        Bv = fmaf(Bv, a, b);
    }
    {
        const float Au = qdpp<0x90>(A), Bu = qdpp<0x90>(Bv);
        if (seg >= 1) { const float Ac = A; A = Au * Ac; Bv = fmaf(Bu, Ac, Bv); }
        const float Au2 = qdpp<0x44>(A), Bu2 = qdpp<0x44>(Bv);
        if (seg >= 2) { const float Ac = A; A = Au2 * Ac; Bv = fmaf(Bu2, Ac, Bv); }
    }
    float Ae = qdpp<0x90>(A), Be = qdpp<0x90>(Bv);
    if (seg == 0) { Ae = 1.0f; Be = 0.0f; }
    float cc = fmaf(Ae, carry, Be);
    #pragma unroll
    for (int i = 0; i < 16; ++i) {
        const bool on = (bits >> i) & 1u;
        const float a = on ? a1v : a0v;
        const float b = on ? b1v : b0v;
        cc = fmaf(a, cc, b);
        sh[(seg * 16 + i) * SS + col0] = cc;
    }
    carry = qdpp<0xFF>(cc);   // broadcast quad lane-3 (seg=3) final state
}

__global__ void __launch_bounds__(256)
// min 3 waves/EU (budget ~170 regs — fits the ~150-reg demand, NO spill;
// round 1/2 proved a 128 budget spills ~1GB of scratch traffic).
// max 4: if the allocator lands <=128, LDS (39.2KB) still admits 4 blocks/CU.
__attribute__((amdgpu_waves_per_eu(3, 4)))
gru_fused(const float* __restrict__ x, const int* __restrict__ p,
               const float* __restrict__ w1z0, const float* __restrict__ b1z0,
               const float* __restrict__ w1h0, const float* __restrict__ b1h0,
               const float* __restrict__ w1z1, const float* __restrict__ b1z1,
               const float* __restrict__ w1h1, const float* __restrict__ b1h1,
               const float* __restrict__ w1o,  const float* __restrict__ b1o,
               const float* __restrict__ w2z0, const float* __restrict__ b2z0,
               const float* __restrict__ w2h0, const float* __restrict__ b2h0,
               const float* __restrict__ w2z1, const float* __restrict__ b2z1,
               const float* __restrict__ w2h1, const float* __restrict__ b2h1,
               const float* __restrict__ w2o,  const float* __restrict__ b2o,
               float* __restrict__ out, float* __restrict__ ws)
{
    const int  b  = blockIdx.x;
    const bool pm = (blockIdx.y != 0);

    const float* wz0 = pm ? w2z0 : w1z0;
    const float* bz0 = pm ? b2z0 : b1z0;
    const float* wh0 = pm ? w2h0 : w1h0;
    const float* bh0 = pm ? b2h0 : b1h0;
    const float* wz1 = pm ? w2z1 : w1z1;
    const float* bz1 = pm ? b2z1 : b1z1;
    const float* wh1 = pm ? w2h1 : w1h1;
    const float* bh1 = pm ? b2h1 : b1h1;
    const float* wo  = pm ? w2o  : w1o;
    const float* bov = pm ? b2o  : b1o;

    const int tid  = threadIdx.x;
    const int lane = tid & 63;
    const int tg   = tid >> 6;          // wave id; owns t-block [16*tg, 16*tg+16)
    const int q    = lane >> 4;         // MFMA quad (t sub-block)
    const int n    = lane & 15;         // MFMA col (h low bits)
    const int seg  = lane & 3;          // P1 segment
    const int hidx = (tg << 4) | (lane >> 2);

    __shared__ __align__(16) float s_h[2 * TT * SS];   // double-buffered h0 (34.8 KB)
    __shared__ unsigned long long s_xb[LL / 64];       // bit-packed (permuted) x row (256 B)
    __shared__ float2 s_w[2][4][HH];                   // per-wave-block scan transforms (A,B)
    __shared__ float s_red[8];

    const float* xrow = x + (size_t)b * LL;

    // ---- stage x row as BITS (ballot-packed; pm branch gathers once here) ----
    #pragma unroll
    for (int g = 0; g < 8; ++g) {
        const int idx = g * 256 + tid;          // wave covers 64 consecutive t
        const int src = pm ? p[idx] : idx;
        const unsigned long long m = __ballot(xrow[src] != 0.0f);
        if (lane == 0) s_xb[g * 4 + tg] = m;
    }
    const unsigned* bw = (const unsigned*)s_xb;

    // ---- layer-0 LUT per hidx (x is bernoulli {0,1}) ----
    const float z0v = rcp_(1.0f + __expf(-bz0[hidx]));
    const float z1v = rcp_(1.0f + __expf(-(wz0[hidx] + bz0[hidx])));
    const float a0v = 1.0f - z0v, b0v = z0v * bh0[hidx];
    const float a1v = 1.0f - z1v, b1v = z1v * (wh0[hidx] + bh0[hidx]);

    // ---- layer-1 biases + output weights (MFMA (ht,n) mapping) ----
    float rbz1[4], rbh1[4], rwo4[4];
    #pragma unroll
    for (int ht = 0; ht < 4; ++ht) {
        rbz1[ht] = bz1[ht * 16 + n];
        rbh1[ht] = bh1[ht * 16 + n];
        rwo4[ht] = wo[ht * 16 + n];
    }
    const float bo = bov[0];

    // ---- layer-1 weight B-fragments, RNE hi only ----
    bf16x8 wfz[2][4], wfh[2][4];
    for (int ks = 0; ks < 2; ++ks) {
        for (int ht = 0; ht < 4; ++ht) {
            #pragma unroll
            for (int j = 0; j < 8; ++j) {
                const int kk = ks * 32 + q * 8 + j;
                const int hh = ht * 16 + n;
                wfz[ks][ht][j] = f2bf_rne(wz1[kk * HH + hh]);
                wfh[ks][ht][j] = f2bf_rne(wh1[kk * HH + hh]);
            }
        }
    }

    float carry0 = 0.0f;
    float carry1[4] = {0.0f, 0.0f, 0.0f, 0.0f};   // per ht (h = ht*16+n)
    f32x4 ga[4], gb[4];                            // layer-1 gates (a,b), chunk-persistent
    float Aqe[4], Bqe[4];                          // exclusive-q transforms, chunk-persistent
    float lsum = 0.0f, lsum2 = 0.0f;
    float* outp = out + (pm ? 1 : 0);
    const int t0 = tg * 16;
    const int col0 = hidx ^ ((seg & 1) << 4);      // s_h col swizzle (write side)

    // G2: apply layer-1 scan for chunk cm (gates/Aqe of cm live in registers),
    // fused output projection (DPP shift-reduce over n) + store.
    auto g2_step = [&](int cm) {
        const int buf = cm & 1;
        float Acm[4] = {1,1,1,1}, Bcm[4] = {0,0,0,0};
        float Ap[4], Bp[4];
        #pragma unroll
        for (int w = 0; w < 4; ++w) {
            #pragma unroll
            for (int ht = 0; ht < 4; ++ht) {
                if (w == tg) { Ap[ht] = Acm[ht]; Bp[ht] = Bcm[ht]; }
                const float2 ab = s_w[buf][w][ht * 16 + n];
                Bcm[ht] = fmaf(ab.x, Bcm[ht], ab.y);
                Acm[ht] *= ab.x;
            }
        }
        float vo[4] = {0,0,0,0};
        #pragma unroll
        for (int ht = 0; ht < 4; ++ht) {
            float cc = fmaf(Aqe[ht], fmaf(Ap[ht], carry1[ht], Bp[ht]), Bqe[ht]);
            #pragma unroll
            for (int r = 0; r < 4; ++r) {
                cc = fmaf(ga[ht][r], cc, gb[ht][r]);
                vo[r] = fmaf(cc, rwo4[ht], vo[r]);
            }
            carry1[ht] = fmaf(Acm[ht], carry1[ht], Bcm[ht]);
        }
        // shift-reduce over n (16-lane rows) on the VALU: lane n==15 gets the sum
        #pragma unroll
        for (int r = 0; r < 4; ++r) {
            vo[r] += rshr<1>(vo[r]);
            vo[r] += rshr<2>(vo[r]);
            vo[r] += rshr<4>(vo[r]);
            vo[r] += rshr<8>(vo[r]);
        }
        if (n == 15) {
            #pragma unroll
            for (int r = 0; r < 4; ++r) {
                const float v = vo[r] + bo;
                outp[((size_t)b * LL + cm * TT + t0 + q * 4 + r) * 2] = v;
                lsum += v;
                lsum2 = fmaf(v, v, lsum2);
            }
        }
    };

    __syncthreads();   // s_xb staged

    // ---- prologue: P1(0) -> s_h buf 0 ----
    p1_scan(bw, 0, a0v, b0v, a1v, b1v, seg, col0, carry0, s_h);
    __syncthreads();

    for (int c = 0; c < NCH; ++c) {
        const int cp1 = c + 1;

        // ---- G2(c-1): uses previous chunk's gates (still in registers) ----
        if (c > 0) g2_step(c - 1);

        // ---- G1(c): MFMA + gates + per-wave scan transforms ----
        {
            #pragma unroll
            for (int ht = 0; ht < 4; ++ht) {
                ga[ht] = (f32x4){rbz1[ht], rbz1[ht], rbz1[ht], rbz1[ht]};
                gb[ht] = (f32x4){rbh1[ht], rbh1[ht], rbh1[ht], rbh1[ht]};
            }
            const float* shR = s_h + (c & 1) * (TT * SS);
            const int qs = q ^ ((tg & 1) << 1);   // undo s_h col swizzle (t>>4 == tg)
            #pragma unroll
            for (int ks = 0; ks < 2; ++ks) {
                const float* ap = &shR[(t0 + n) * SS + ks * 32 + qs * 8];
                const float4 av0 = *(const float4*)ap;
                const float4 av1 = *(const float4*)(ap + 4);
                float af[8] = {av0.x, av0.y, av0.z, av0.w, av1.x, av1.y, av1.z, av1.w};
                bf16x8 ahi, alo;
                #pragma unroll
                for (int j = 0; j < 8; ++j) {
                    union { float f; unsigned u; } uf; uf.f = af[j];
                    ahi[j] = (short)(uf.u >> 16);                       // truncate
                    union { unsigned u; float f; } hf; hf.u = uf.u & 0xffff0000u;
                    const float rem = af[j] - hf.f;                     // exact
                    union { float f; unsigned u; } ur; ur.f = rem;
                    alo[j] = (short)(ur.u >> 16);
                }
                #pragma unroll
                for (int ht = 0; ht < 4; ++ht) {
                    ga[ht] = __builtin_amdgcn_mfma_f32_16x16x32_bf16(ahi, wfz[ks][ht], ga[ht], 0, 0, 0);
                    ga[ht] = __builtin_amdgcn_mfma_f32_16x16x32_bf16(alo, wfz[ks][ht], ga[ht], 0, 0, 0);
                    gb[ht] = __builtin_amdgcn_mfma_f32_16x16x32_bf16(ahi, wfh[ks][ht], gb[ht], 0, 0, 0);
                    gb[ht] = __builtin_amdgcn_mfma_f32_16x16x32_bf16(alo, wfh[ks][ht], gb[ht], 0, 0, 0);
                }
            }
            // gates in place: a = 1-sigmoid(v) = rcp(1+exp(v)); b = htl - a*htl
            #pragma unroll
            for (int ht = 0; ht < 4; ++ht) {
                #pragma unroll
                for (int r = 0; r < 4; ++r) {
                    const float v   = ga[ht][r];
                    const float a   = rcp_(1.0f + __expf(v));
                    const float htl = gb[ht][r];
                    ga[ht][r] = a;
                    gb[ht][r] = fmaf(-a, htl, htl);
                }
            }
            // compose own 4 r-steps per ht
            float Aq[4], Bq[4];
            #pragma unroll
            for (int ht = 0; ht < 4; ++ht) {
                float A = 1.0f, B = 0.0f;
                #pragma unroll
                for (int r = 0; r < 4; ++r) {
                    B = fmaf(ga[ht][r], B, gb[ht][r]);
                    A = A * ga[ht][r];
                }
                Aq[ht] = A; Bq[ht] = B;
            }
            // inclusive Hillis-Steele over q (strides 16, 32 lanes)
            #pragma unroll
            for (int ht = 0; ht < 4; ++ht) {
                const float Au = __shfl_up(Aq[ht], 16), Bu = __shfl_up(Bq[ht], 16);
                if (q >= 1) { const float Ac = Aq[ht]; Aq[ht] = Ac * Au; Bq[ht] = fmaf(Ac, Bu, Bq[ht]); }
            }
            #pragma unroll
            for (int ht = 0; ht < 4; ++ht) {
                const float Au = __shfl_up(Aq[ht], 32), Bu = __shfl_up(Bq[ht], 32);
                if (q >= 2) { const float Ac = Aq[ht]; Aq[ht] = Ac * Au; Bq[ht] = fmaf(Ac, Bu, Bq[ht]); }
            }
            // exclusive-q transforms (persist to G2)
            #pragma unroll
            for (int ht = 0; ht < 4; ++ht) {
                const float Ae = __shfl_up(Aq[ht], 16), Be = __shfl_up(Bq[ht], 16);
                Aqe[ht] = (q == 0) ? 1.0f : Ae;
                Bqe[ht] = (q == 0) ? 0.0f : Be;
            }
            // q==3 lanes publish the wave-block inclusive transform
            if (q == 3) {
                #pragma unroll
                for (int ht = 0; ht < 4; ++ht)
                    s_w[c & 1][tg][ht * 16 + n] = make_float2(Aq[ht], Bq[ht]);
            }
        }

        // ---- P1(c+1) -> other s_h buffer (reads bit-packed x) ----
        if (cp1 < NCH)
            p1_scan(bw, cp1, a0v, b0v, a1v, b1v, seg, col0, carry0,
                    s_h + (cp1 & 1) * (TT * SS));

        __syncthreads();
    }

    // ---- G2 for the last chunk ----
    g2_step(NCH - 1);

    // ---- block partial (sum, sumsq) -> ws slots (plain stores) ----
    #pragma unroll
    for (int o = 32; o; o >>= 1) {
        lsum  += __shfl_down(lsum, o);
        lsum2 += __shfl_down(lsum2, o);
    }
    if (lane == 0) { s_red[tg] = lsum; s_red[4 + tg] = lsum2; }
    __syncthreads();
    if (tid == 0) {
        const int gb2 = b * 2 + (pm ? 1 : 0);
        ws[2 * gb2]     = s_red[0] + s_red[1] + s_red[2] + s_red[3];
        ws[2 * gb2 + 1] = s_red[4] + s_red[5] + s_red[6] + s_red[7];
    }
}

// Fold the 512 block-partials (redundantly per block), normalize in-place.
__global__ void normalize_k(float* __restrict__ out, const float* __restrict__ ws)
{
    __shared__ float s_red[8];
    float s = 0.0f, s2 = 0.0f;
    for (int i = threadIdx.x; i < 2 * BB; i += 256) {
        s  += ws[2 * i];
        s2 += ws[2 * i + 1];
    }
    #pragma unroll
    for (int o = 32; o; o >>= 1) {
        s  += __shfl_down(s, o);
        s2 += __shfl_down(s2, o);
    }
    const int wid = threadIdx.x >> 6;
    if ((threadIdx.x & 63) == 0) { s_red[wid] = s; s_red[4 + wid] = s2; }
    __syncthreads();
    const float tot  = s_red[0] + s_red[1] + s_red[2] + s_red[3];
    const float tot2 = s_red[4] + s_red[5] + s_red[6] + s_red[7];
    const float N    = (float)NTOT;
    const float mean = tot / N;
    const float var  = (tot2 - N * mean * mean) / (N - 1.0f);
    const float inv  = rsqrtf(var);

    const int i = blockIdx.x * blockDim.x + threadIdx.x;   // exactly NTOT/4 threads
    float4* o4 = (float4*)out;
    float4 v = o4[i];
    v.x = (v.x - mean) * inv;
    v.y = (v.y - mean) * inv;
    v.z = (v.z - mean) * inv;
    v.w = (v.w - mean) * inv;
    o4[i] = v;
}

extern "C" void kernel_launch(void* const* d_in, const int* in_sizes, int n_in,
                              void* d_out, int out_size, void* d_ws, size_t ws_size,
                              hipStream_t stream)
{
    (void)in_sizes; (void)n_in; (void)out_size; (void)ws_size;
    const float* x = (const float*)d_in[0];
    const int*   p = (const int*)d_in[1];
    float* out = (float*)d_out;
    float* ws  = (float*)d_ws;

    dim3 grid(BB, 2);
    gru_fused<<<grid, 256, 0, stream>>>(
        x, p,
        (const float*)d_in[2],  (const float*)d_in[3],
        (const float*)d_in[4],  (const float*)d_in[5],
        (const float*)d_in[6],  (const float*)d_in[7],
        (const float*)d_in[8],  (const float*)d_in[9],
        (const float*)d_in[10], (const float*)d_in[11],
        (const float*)d_in[12], (const float*)d_in[13],
        (const float*)d_in[14], (const float*)d_in[15],
        (const float*)d_in[16], (const float*)d_in[17],
        (const float*)d_in[18], (const float*)d_in[19],
        (const float*)d_in[20], (const float*)d_in[21],
        out, ws);

    normalize_k<<<NTOT / 4 / 256, 256, 0, stream>>>(out, ws);
}

// Round 4
// 201.983 us; speedup vs baseline: 1.8933x; 1.3921x over previous
//
#include <hip/hip_runtime.h>

#define BB 256
#define LL 2048
#define HH 64
#define TT 64            // chunk length along L
#define SS 68            // padded LDS row stride (floats)
#define NCH (LL / TT)    // 32 chunks
#define NTOT (BB * LL * 2)

typedef __attribute__((ext_vector_type(8))) short bf16x8;
typedef __attribute__((ext_vector_type(4))) float f32x4;

__device__ __forceinline__ float rcp_(float x) { return __builtin_amdgcn_rcpf(x); }

// RNE fp32->bf16 (weights only, outside hot loop)
__device__ __forceinline__ short f2bf_rne(float f) {
    union { float f; unsigned u; } v; v.f = f;
    unsigned r = v.u + 0x7fff + ((v.u >> 16) & 1);
    return (short)(r >> 16);
}

// pack hi16(f_hi):hi16(f_lo) into one dword with a single v_perm_b32
__device__ __forceinline__ unsigned perm_hi16(float f_hi, float f_lo) {
    union { float f; unsigned u; } a, b;
    a.f = f_hi; b.f = f_lo;
    return __builtin_amdgcn_perm(a.u, b.u, 0x07060302u);
}

// DPP quad_perm: 0x90 = shift-up-1, 0x44 = shift-up-2, 0xFF = bcast lane3 of quad.
template<int CTRL>
__device__ __forceinline__ float qdpp(float x) {
    union { float f; int i; } u, r;
    u.f = x;
    r.i = __builtin_amdgcn_update_dpp(0, u.i, CTRL, 0xF, 0xF, false);
    return r.f;
}

// DPP row_shr:D with zero bound (used by G2's n-reduce).
template<int D>
__device__ __forceinline__ float rshr(float x) {
    union { float f; int i; } u, r;
    u.f = x;
    r.i = __builtin_amdgcn_update_dpp(0, u.i, 0x110 | D, 0xF, 0xF, true);
    return r.f;
}

// Layer-0 gates (Bernoulli bit-LUT) + 64-step chunk scan (16 local + quad scan
// via DPP). Gates are recomputed from the packed bits in the apply loop.
__device__ __forceinline__ void p1_scan(const unsigned* __restrict__ bw, int c,
                                        float a0v, float b0v, float a1v, float b1v,
                                        int seg, int col0, float& carry, float* sh)
{
    const unsigned bits = (bw[c * 2 + (seg >> 1)] >> ((seg & 1) << 4)) & 0xffffu;
    float A = 1.0f, Bv = 0.0f;
    #pragma unroll
    for (int i = 0; i < 16; ++i) {
        const bool on = (bits >> i) & 1u;
        const float a = on ? a1v : a0v;
        const float b = on ? b1v : b0v;
        A  = A * a;
        Bv = fmaf(Bv, a, b);
    }
    {
        const float Au = qdpp<0x90>(A), Bu = qdpp<0x90>(Bv);
        if (seg >= 1) { const float Ac = A; A = Au * Ac; Bv = fmaf(Bu, Ac, Bv); }
        const float Au2 = qdpp<0x44>(A), Bu2 = qdpp<0x44>(Bv);
        if (seg >= 2) { const float Ac = A; A = Au2 * Ac; Bv = fmaf(Bu2, Ac, Bv); }
    }
    float Ae = qdpp<0x90>(A), Be = qdpp<0x90>(Bv);
    if (seg == 0) { Ae = 1.0f; Be = 0.0f; }
    float cc = fmaf(Ae, carry, Be);
    #pragma unroll
    for (int i = 0; i < 16; ++i) {
        const bool on = (bits >> i) & 1u;
        const float a = on ? a1v : a0v;
        const float b = on ? b1v : b0v;
        cc = fmaf(a, cc, b);
        sh[(seg * 16 + i) * SS + col0] = cc;
    }
    carry = qdpp<0xFF>(cc);   // broadcast quad lane-3 (seg=3) final state
}

// H-split: blockIdx.y = pm + 2*hh. Each block computes the FULL layer-0 scan
// (cheap, duplicated across the 2 h-halves) but only half the layer-1
// MFMA/gates/scan/projection (ht = 0..1 covering h = hh*32 .. hh*32+31).
// Partial projections are atomicAdd'ed into pre-zeroed out.
// Grid = 256*2*2 = 1024 blocks -> 4 blocks/CU (the old 512-block grid capped
// occupancy at 2 blocks/CU regardless of registers). Demand ~110 regs fits
// the 128-reg budget 4 waves/SIMD requires (NO spill, unlike rounds 1-3).
__global__ void __launch_bounds__(256)
__attribute__((amdgpu_waves_per_eu(4, 4)))
gru_fused(const float* __restrict__ x, const int* __restrict__ p,
               const float* __restrict__ w1z0, const float* __restrict__ b1z0,
               const float* __restrict__ w1h0, const float* __restrict__ b1h0,
               const float* __restrict__ w1z1, const float* __restrict__ b1z1,
               const float* __restrict__ w1h1, const float* __restrict__ b1h1,
               const float* __restrict__ w1o,  const float* __restrict__ b1o,
               const float* __restrict__ w2z0, const float* __restrict__ b2z0,
               const float* __restrict__ w2h0, const float* __restrict__ b2h0,
               const float* __restrict__ w2z1, const float* __restrict__ b2z1,
               const float* __restrict__ w2h1, const float* __restrict__ b2h1,
               const float* __restrict__ w2o,  const float* __restrict__ b2o,
               float* __restrict__ out, float* __restrict__ ws)
{
    (void)ws;
    const int  b  = blockIdx.x;
    const bool pm = (blockIdx.y & 1) != 0;
    const int  hh = blockIdx.y >> 1;     // h-half: channels hh*32 .. hh*32+31

    const float* wz0 = pm ? w2z0 : w1z0;
    const float* bz0 = pm ? b2z0 : b1z0;
    const float* wh0 = pm ? w2h0 : w1h0;
    const float* bh0 = pm ? b2h0 : b1h0;
    const float* wz1 = pm ? w2z1 : w1z1;
    const float* bz1 = pm ? b2z1 : b1z1;
    const float* wh1 = pm ? w2h1 : w1h1;
    const float* bh1 = pm ? b2h1 : b1h1;
    const float* wo  = pm ? w2o  : w1o;
    const float* bov = pm ? b2o  : b1o;

    const int tid  = threadIdx.x;
    const int lane = tid & 63;
    const int tg   = tid >> 6;          // wave id; owns t-block [16*tg, 16*tg+16)
    const int q    = lane >> 4;         // MFMA quad (t sub-block)
    const int n    = lane & 15;         // MFMA col (h low bits)
    const int seg  = lane & 3;          // P1 segment
    const int hidx = (tg << 4) | (lane >> 2);   // P1 h channel (all 64)

    __shared__ __align__(16) float s_h[2 * TT * SS];   // double-buffered h0 (34.8 KB)
    __shared__ unsigned long long s_xb[LL / 64];       // bit-packed (permuted) x row
    __shared__ float2 s_w[2][4][2 * 16];               // per-wave scan transforms (A,B)

    const float* xrow = x + (size_t)b * LL;

    // ---- stage x row as BITS (ballot-packed; pm branch gathers once here) ----
    #pragma unroll
    for (int g = 0; g < 8; ++g) {
        const int idx = g * 256 + tid;          // wave covers 64 consecutive t
        const int src = pm ? p[idx] : idx;
        const unsigned long long m = __ballot(xrow[src] != 0.0f);
        if (lane == 0) s_xb[g * 4 + tg] = m;
    }
    const unsigned* bw = (const unsigned*)s_xb;

    // ---- layer-0 LUT per hidx (x is bernoulli {0,1}) ----
    const float z0v = rcp_(1.0f + __expf(-bz0[hidx]));
    const float z1v = rcp_(1.0f + __expf(-(wz0[hidx] + bz0[hidx])));
    const float a0v = 1.0f - z0v, b0v = z0v * bh0[hidx];
    const float a1v = 1.0f - z1v, b1v = z1v * (wh0[hidx] + bh0[hidx]);

    // ---- layer-1 biases + output weights for THIS h-half ----
    float rbz1[2], rbh1[2], rwo4[2];
    #pragma unroll
    for (int ht = 0; ht < 2; ++ht) {
        const int h = hh * 32 + ht * 16 + n;
        rbz1[ht] = bz1[h];
        rbh1[ht] = bh1[h];
        rwo4[ht] = wo[h];
    }
    const float bo = (hh == 0) ? bov[0] : 0.0f;   // bias added once across halves

    // ---- layer-1 weight B-fragments (half), RNE hi only ----
    bf16x8 wfz[2][2], wfh[2][2];
    for (int ks = 0; ks < 2; ++ks) {
        for (int ht = 0; ht < 2; ++ht) {
            #pragma unroll
            for (int j = 0; j < 8; ++j) {
                const int kk = ks * 32 + q * 8 + j;
                const int h  = hh * 32 + ht * 16 + n;
                wfz[ks][ht][j] = f2bf_rne(wz1[kk * HH + h]);
                wfh[ks][ht][j] = f2bf_rne(wh1[kk * HH + h]);
            }
        }
    }

    float carry0 = 0.0f;
    float carry1[2] = {0.0f, 0.0f};
    f32x4 ga[2], gb[2];                // layer-1 gates (a,b), chunk-persistent
    float Aqe[2], Bqe[2];              // exclusive-q transforms, chunk-persistent
    float* outp = out + (pm ? 1 : 0);
    const int t0 = tg * 16;
    const int col0 = hidx ^ ((seg & 1) << 4);      // s_h col swizzle (write side)

    // G2: apply layer-1 scan for chunk cm, fused half-projection, atomicAdd.
    auto g2_step = [&](int cm) {
        const int buf = cm & 1;
        float Acm[2] = {1, 1}, Bcm[2] = {0, 0};
        float Ap[2], Bp[2];
        #pragma unroll
        for (int w = 0; w < 4; ++w) {
            #pragma unroll
            for (int ht = 0; ht < 2; ++ht) {
                if (w == tg) { Ap[ht] = Acm[ht]; Bp[ht] = Bcm[ht]; }
                const float2 ab = s_w[buf][w][ht * 16 + n];
                Bcm[ht] = fmaf(ab.x, Bcm[ht], ab.y);
                Acm[ht] *= ab.x;
            }
        }
        float vo[4] = {0, 0, 0, 0};
        #pragma unroll
        for (int ht = 0; ht < 2; ++ht) {
            float cc = fmaf(Aqe[ht], fmaf(Ap[ht], carry1[ht], Bp[ht]), Bqe[ht]);
            #pragma unroll
            for (int r = 0; r < 4; ++r) {
                cc = fmaf(ga[ht][r], cc, gb[ht][r]);
                vo[r] = fmaf(cc, rwo4[ht], vo[r]);
            }
            carry1[ht] = fmaf(Acm[ht], carry1[ht], Bcm[ht]);
        }
        // shift-reduce over n (16-lane rows): lane n==15 gets the half-sum
        #pragma unroll
        for (int r = 0; r < 4; ++r) {
            vo[r] += rshr<1>(vo[r]);
            vo[r] += rshr<2>(vo[r]);
            vo[r] += rshr<4>(vo[r]);
            vo[r] += rshr<8>(vo[r]);
        }
        if (n == 15) {
            #pragma unroll
            for (int r = 0; r < 4; ++r)
                atomicAdd(&outp[((size_t)b * LL + cm * TT + t0 + q * 4 + r) * 2],
                          vo[r] + bo);
        }
    };

    __syncthreads();   // s_xb staged

    // ---- prologue: P1(0) -> s_h buf 0 ----
    p1_scan(bw, 0, a0v, b0v, a1v, b1v, seg, col0, carry0, s_h);
    __syncthreads();

    for (int c = 0; c < NCH; ++c) {
        const int cp1 = c + 1;

        // ---- G2(c-1): uses previous chunk's gates (still in registers) ----
        if (c > 0) g2_step(c - 1);

        // ---- G1(c): MFMA + gates + per-wave scan transforms (half) ----
        {
            #pragma unroll
            for (int ht = 0; ht < 2; ++ht) {
                ga[ht] = (f32x4){rbz1[ht], rbz1[ht], rbz1[ht], rbz1[ht]};
                gb[ht] = (f32x4){rbh1[ht], rbh1[ht], rbh1[ht], rbh1[ht]};
            }
            const float* shR = s_h + (c & 1) * (TT * SS);
            const int qs = q ^ ((tg & 1) << 1);   // undo s_h col swizzle
            #pragma unroll
            for (int ks = 0; ks < 2; ++ks) {
                const float* ap = &shR[(t0 + n) * SS + ks * 32 + qs * 8];
                const float4 av0 = *(const float4*)ap;
                const float4 av1 = *(const float4*)(ap + 4);
                float af[8] = {av0.x, av0.y, av0.z, av0.w, av1.x, av1.y, av1.z, av1.w};
                // hi16 pack via v_perm; exact remainder -> lo bf16
                union { bf16x8 v; unsigned d[4]; } ahi, alo;
                float rem[8];
                #pragma unroll
                for (int j = 0; j < 8; ++j) {
                    union { float f; unsigned u; } uf; uf.f = af[j];
                    union { unsigned u; float f; } hf; hf.u = uf.u & 0xffff0000u;
                    rem[j] = af[j] - hf.f;                     // exact
                }
                #pragma unroll
                for (int k = 0; k < 4; ++k) {
                    ahi.d[k] = perm_hi16(af[2 * k + 1], af[2 * k]);
                    alo.d[k] = perm_hi16(rem[2 * k + 1], rem[2 * k]);
                }
                #pragma unroll
                for (int ht = 0; ht < 2; ++ht) {
                    ga[ht] = __builtin_amdgcn_mfma_f32_16x16x32_bf16(ahi.v, wfz[ks][ht], ga[ht], 0, 0, 0);
                    ga[ht] = __builtin_amdgcn_mfma_f32_16x16x32_bf16(alo.v, wfz[ks][ht], ga[ht], 0, 0, 0);
                    gb[ht] = __builtin_amdgcn_mfma_f32_16x16x32_bf16(ahi.v, wfh[ks][ht], gb[ht], 0, 0, 0);
                    gb[ht] = __builtin_amdgcn_mfma_f32_16x16x32_bf16(alo.v, wfh[ks][ht], gb[ht], 0, 0, 0);
                }
            }
            // gates in place: a = 1-sigmoid(v) = rcp(1+exp(v)); b = htl - a*htl
            #pragma unroll
            for (int ht = 0; ht < 2; ++ht) {
                #pragma unroll
                for (int r = 0; r < 4; ++r) {
                    const float v   = ga[ht][r];
                    const float a   = rcp_(1.0f + __expf(v));
                    const float htl = gb[ht][r];
                    ga[ht][r] = a;
                    gb[ht][r] = fmaf(-a, htl, htl);
                }
            }
            // compose own 4 r-steps per ht
            float Aq[2], Bq[2];
            #pragma unroll
            for (int ht = 0; ht < 2; ++ht) {
                float A = 1.0f, B = 0.0f;
                #pragma unroll
                for (int r = 0; r < 4; ++r) {
                    B = fmaf(ga[ht][r], B, gb[ht][r]);
                    A = A * ga[ht][r];
                }
                Aq[ht] = A; Bq[ht] = B;
            }
            // inclusive Hillis-Steele over q (strides 16, 32 lanes)
            #pragma unroll
            for (int ht = 0; ht < 2; ++ht) {
                const float Au = __shfl_up(Aq[ht], 16), Bu = __shfl_up(Bq[ht], 16);
                if (q >= 1) { const float Ac = Aq[ht]; Aq[ht] = Ac * Au; Bq[ht] = fmaf(Ac, Bu, Bq[ht]); }
            }
            #pragma unroll
            for (int ht = 0; ht < 2; ++ht) {
                const float Au = __shfl_up(Aq[ht], 32), Bu = __shfl_up(Bq[ht], 32);
                if (q >= 2) { const float Ac = Aq[ht]; Aq[ht] = Ac * Au; Bq[ht] = fmaf(Ac, Bu, Bq[ht]); }
            }
            // exclusive-q transforms (persist to G2)
            #pragma unroll
            for (int ht = 0; ht < 2; ++ht) {
                const float Ae = __shfl_up(Aq[ht], 16), Be = __shfl_up(Bq[ht], 16);
                Aqe[ht] = (q == 0) ? 1.0f : Ae;
                Bqe[ht] = (q == 0) ? 0.0f : Be;
            }
            // q==3 lanes publish the wave-block inclusive transform
            if (q == 3) {
                #pragma unroll
                for (int ht = 0; ht < 2; ++ht)
                    s_w[c & 1][tg][ht * 16 + n] = make_float2(Aq[ht], Bq[ht]);
            }
        }

        // ---- P1(c+1) -> other s_h buffer (reads bit-packed x) ----
        if (cp1 < NCH)
            p1_scan(bw, cp1, a0v, b0v, a1v, b1v, seg, col0, carry0,
                    s_h + (cp1 & 1) * (TT * SS));

        __syncthreads();
    }

    // ---- G2 for the last chunk ----
    g2_step(NCH - 1);
}

// Zero out before atomic accumulation (separate launch = ordering barrier).
__global__ void zero_k(float* __restrict__ out)
{
    ((float4*)out)[blockIdx.x * 256 + threadIdx.x] = (float4){0.f, 0.f, 0.f, 0.f};
}

// Per-block (sum, sumsq) over the COMPLETED out -> 512 ws partial pairs.
__global__ void reduce_k(const float* __restrict__ out, float* __restrict__ ws)
{
    __shared__ float s_red[8];
    const float4* o4 = (const float4*)(out + blockIdx.x * (NTOT / 512));
    float s = 0.0f, s2 = 0.0f;
    #pragma unroll
    for (int i = 0; i < NTOT / 512 / 4 / 256; ++i) {
        const float4 v = o4[threadIdx.x + 256 * i];
        s  += (v.x + v.y) + (v.z + v.w);
        s2 += fmaf(v.x, v.x, v.y * v.y) + fmaf(v.z, v.z, v.w * v.w);
    }
    #pragma unroll
    for (int o = 32; o; o >>= 1) {
        s  += __shfl_down(s, o);
        s2 += __shfl_down(s2, o);
    }
    const int wid = threadIdx.x >> 6;
    if ((threadIdx.x & 63) == 0) { s_red[wid] = s; s_red[4 + wid] = s2; }
    __syncthreads();
    if (threadIdx.x == 0) {
        ws[2 * blockIdx.x]     = s_red[0] + s_red[1] + s_red[2] + s_red[3];
        ws[2 * blockIdx.x + 1] = s_red[4] + s_red[5] + s_red[6] + s_red[7];
    }
}

// Fold the 512 block-partials (redundantly per block), normalize in-place.
__global__ void normalize_k(float* __restrict__ out, const float* __restrict__ ws)
{
    __shared__ float s_red[8];
    float s = 0.0f, s2 = 0.0f;
    for (int i = threadIdx.x; i < 2 * BB; i += 256) {
        s  += ws[2 * i];
        s2 += ws[2 * i + 1];
    }
    #pragma unroll
    for (int o = 32; o; o >>= 1) {
        s  += __shfl_down(s, o);
        s2 += __shfl_down(s2, o);
    }
    const int wid = threadIdx.x >> 6;
    if ((threadIdx.x & 63) == 0) { s_red[wid] = s; s_red[4 + wid] = s2; }
    __syncthreads();
    const float tot  = s_red[0] + s_red[1] + s_red[2] + s_red[3];
    const float tot2 = s_red[4] + s_red[5] + s_red[6] + s_red[7];
    const float N    = (float)NTOT;
    const float mean = tot / N;
    const float var  = (tot2 - N * mean * mean) / (N - 1.0f);
    const float inv  = rsqrtf(var);

    const int i = blockIdx.x * blockDim.x + threadIdx.x;   // exactly NTOT/4 threads
    float4* o4 = (float4*)out;
    float4 v = o4[i];
    v.x = (v.x - mean) * inv;
    v.y = (v.y - mean) * inv;
    v.z = (v.z - mean) * inv;
    v.w = (v.w - mean) * inv;
    o4[i] = v;
}

extern "C" void kernel_launch(void* const* d_in, const int* in_sizes, int n_in,
                              void* d_out, int out_size, void* d_ws, size_t ws_size,
                              hipStream_t stream)
{
    (void)in_sizes; (void)n_in; (void)out_size; (void)ws_size;
    const float* x = (const float*)d_in[0];
    const int*   p = (const int*)d_in[1];
    float* out = (float*)d_out;
    float* ws  = (float*)d_ws;

    zero_k<<<NTOT / 4 / 256, 256, 0, stream>>>(out);

    dim3 grid(BB, 4);   // y = pm + 2*hh
    gru_fused<<<grid, 256, 0, stream>>>(
        x, p,
        (const float*)d_in[2],  (const float*)d_in[3],
        (const float*)d_in[4],  (const float*)d_in[5],
        (const float*)d_in[6],  (const float*)d_in[7],
        (const float*)d_in[8],  (const float*)d_in[9],
        (const float*)d_in[10], (const float*)d_in[11],
        (const float*)d_in[12], (const float*)d_in[13],
        (const float*)d_in[14], (const float*)d_in[15],
        (const float*)d_in[16], (const float*)d_in[17],
        (const float*)d_in[18], (const float*)d_in[19],
        (const float*)d_in[20], (const float*)d_in[21],
        out, ws);

    reduce_k<<<512, 256, 0, stream>>>(out, ws);
    normalize_k<<<NTOT / 4 / 256, 256, 0, stream>>>(out, ws);
}

// Round 5
// 184.811 us; speedup vs baseline: 2.0692x; 1.0929x over previous
//
#include <hip/hip_runtime.h>

#define BB 256
#define LL 2048
#define HH 64
#define TT 64            // chunk length along L
#define SS 68            // padded LDS row stride (floats)
#define NCH (LL / TT)    // 32 chunks
#define NTOT (BB * LL * 2)

typedef __attribute__((ext_vector_type(8))) short bf16x8;
typedef __attribute__((ext_vector_type(4))) float f32x4;

__device__ __forceinline__ float rcp_(float x) { return __builtin_amdgcn_rcpf(x); }

// RNE fp32->bf16 (weights only, outside hot loop)
__device__ __forceinline__ short f2bf_rne(float f) {
    union { float f; unsigned u; } v; v.f = f;
    unsigned r = v.u + 0x7fff + ((v.u >> 16) & 1);
    return (short)(r >> 16);
}

// pack hi16(f_hi):hi16(f_lo) into one dword with a single v_perm_b32
__device__ __forceinline__ unsigned perm_hi16(float f_hi, float f_lo) {
    union { float f; unsigned u; } a, b;
    a.f = f_hi; b.f = f_lo;
    return __builtin_amdgcn_perm(a.u, b.u, 0x07060302u);
}

// DPP row_shr:D with zero bound: lane i receives lane i-D within its 16-lane row.
template<int D>
__device__ __forceinline__ float rshr(float x) {
    union { float f; int i; } u, r;
    u.f = x;
    r.i = __builtin_amdgcn_update_dpp(0, u.i, 0x110 | D, 0xF, 0xF, true);
    return r.f;
}

// Layer-0 gates (Bernoulli bit-LUT) + 64-step chunk scan split over 8 waves:
// each lane owns 8 local steps (seg = lane&7, 8 segments per h channel);
// guarded row_shr DPP scan over segments (strides 1,2,4 stay inside the
// 8-lane h-group because seg>=D guards them). Store swizzle col = h ^ (seg<<2):
// store bank = (4i + col) mod 32 -> exactly 2 lanes/bank (free).
__device__ __forceinline__ void p1_scan(const unsigned* __restrict__ bw, int c,
                                        float a0v, float b0v, float a1v, float b1v,
                                        int seg, int col0, int lane7,
                                        float& carry, float* sh)
{
    const unsigned bits = (bw[c * 2 + (seg >> 2)] >> ((seg & 3) << 3)) & 0xffu;
    float A = 1.0f, Bv = 0.0f;
    #pragma unroll
    for (int i = 0; i < 8; ++i) {
        const bool on = (bits >> i) & 1u;
        const float a = on ? a1v : a0v;
        const float b = on ? b1v : b0v;
        A  = A * a;
        Bv = fmaf(Bv, a, b);
    }
    // inclusive Hillis-Steele over 8 segments (strides 1,2,4)
    {
        const float Au = rshr<1>(A), Bu = rshr<1>(Bv);
        if (seg >= 1) { const float Ac = A; A = Au * Ac; Bv = fmaf(Bu, Ac, Bv); }
    }
    {
        const float Au = rshr<2>(A), Bu = rshr<2>(Bv);
        if (seg >= 2) { const float Ac = A; A = Au * Ac; Bv = fmaf(Bu, Ac, Bv); }
    }
    {
        const float Au = rshr<4>(A), Bu = rshr<4>(Bv);
        if (seg >= 4) { const float Ac = A; A = Au * Ac; Bv = fmaf(Bu, Ac, Bv); }
    }
    // exclusive transform for this segment's incoming state
    float Ae = rshr<1>(A), Be = rshr<1>(Bv);
    if (seg == 0) { Ae = 1.0f; Be = 0.0f; }
    float cc = fmaf(Ae, carry, Be);
    #pragma unroll
    for (int i = 0; i < 8; ++i) {
        const bool on = (bits >> i) & 1u;
        const float a = on ? a1v : a0v;
        const float b = on ? b1v : b0v;
        cc = fmaf(a, cc, b);
        sh[(seg * 8 + i) * SS + col0] = cc;
    }
    carry = __shfl(cc, lane7);   // seg==7 lane of this h-group holds chunk-final state
}

// 8 waves = 4 t-waves x 2 h-halves (in-block H-split):
//   tw = tg&3 owns t rows [tw*16, tw*16+16); hw = tg>>2 owns h [hw*32, hw*32+32).
// Each wave: 2 ht of layer-1 (round-4's proven-no-spill register footprint),
// P1 split 8 ways (8 segs x 8 steps), half-projections combined via a tiny
// LDS buffer with one-chunk deferral (no atomics, no extra barrier).
// Grid 512 blocks x 8 waves = 2 blocks/CU -> 4 waves/SIMD (50% cap).
__global__ void __launch_bounds__(512)
__attribute__((amdgpu_waves_per_eu(4, 4)))
gru_fused(const float* __restrict__ x, const int* __restrict__ p,
               const float* __restrict__ w1z0, const float* __restrict__ b1z0,
               const float* __restrict__ w1h0, const float* __restrict__ b1h0,
               const float* __restrict__ w1z1, const float* __restrict__ b1z1,
               const float* __restrict__ w1h1, const float* __restrict__ b1h1,
               const float* __restrict__ w1o,  const float* __restrict__ b1o,
               const float* __restrict__ w2z0, const float* __restrict__ b2z0,
               const float* __restrict__ w2h0, const float* __restrict__ b2h0,
               const float* __restrict__ w2z1, const float* __restrict__ b2z1,
               const float* __restrict__ w2h1, const float* __restrict__ b2h1,
               const float* __restrict__ w2o,  const float* __restrict__ b2o,
               float* __restrict__ out, float* __restrict__ ws)
{
    const int  b  = blockIdx.x;
    const bool pm = (blockIdx.y != 0);

    const float* wz0 = pm ? w2z0 : w1z0;
    const float* bz0 = pm ? b2z0 : b1z0;
    const float* wh0 = pm ? w2h0 : w1h0;
    const float* bh0 = pm ? b2h0 : b1h0;
    const float* wz1 = pm ? w2z1 : w1z1;
    const float* bz1 = pm ? b2z1 : b1z1;
    const float* wh1 = pm ? w2h1 : w1h1;
    const float* bh1 = pm ? b2h1 : b1h1;
    const float* wo  = pm ? w2o  : w1o;
    const float* bov = pm ? b2o  : b1o;

    const int tid   = threadIdx.x;
    const int lane  = tid & 63;
    const int tg    = tid >> 6;          // wave id (8)
    const int tw    = tg & 3;            // t sub-block wave
    const int hw    = tg >> 2;           // h-half
    const int q     = lane >> 4;         // MFMA quad (t sub-block)
    const int n     = lane & 15;         // MFMA col (h low bits)
    const int seg   = lane & 7;          // P1 segment (8 per h)
    const int hidx  = (tg << 3) | (lane >> 3);   // P1 h channel (0..63)
    const int lane7 = lane | 7;

    __shared__ __align__(16) float s_h[2 * TT * SS];   // double-buffered h0 (34.8 KB)
    __shared__ unsigned long long s_xb[LL / 64];       // bit-packed (permuted) x row
    __shared__ float2 s_w[2][2][4][32];                // [buf][hw][tw][ht*16+n]
    __shared__ float s_o[2][4][16];                    // [buf][tw][q*4+r] hw1 partials
    __shared__ float s_red[16];

    const float* xrow = x + (size_t)b * LL;

    // ---- stage x row as BITS (ballot-packed; pm branch gathers once here) ----
    #pragma unroll
    for (int g = 0; g < 4; ++g) {
        const int idx = g * 512 + tid;
        const int src = pm ? p[idx] : idx;
        const unsigned long long m = __ballot(xrow[src] != 0.0f);
        if (lane == 0) s_xb[g * 8 + tg] = m;
    }
    const unsigned* bw = (const unsigned*)s_xb;

    // ---- layer-0 LUT per hidx (x is bernoulli {0,1}) ----
    const float z0v = rcp_(1.0f + __expf(-bz0[hidx]));
    const float z1v = rcp_(1.0f + __expf(-(wz0[hidx] + bz0[hidx])));
    const float a0v = 1.0f - z0v, b0v = z0v * bh0[hidx];
    const float a1v = 1.0f - z1v, b1v = z1v * (wh0[hidx] + bh0[hidx]);

    // ---- layer-1 biases + output weights for THIS h-half ----
    float rbz1[2], rbh1[2], rwo4[2];
    #pragma unroll
    for (int ht = 0; ht < 2; ++ht) {
        const int h = hw * 32 + ht * 16 + n;
        rbz1[ht] = bz1[h];
        rbh1[ht] = bh1[h];
        rwo4[ht] = wo[h];
    }
    const float bo = bov[0];   // added once, by hw0 at combine time

    // ---- layer-1 weight B-fragments (this half), RNE hi only ----
    bf16x8 wfz[2][2], wfh[2][2];
    for (int ks = 0; ks < 2; ++ks) {
        for (int ht = 0; ht < 2; ++ht) {
            #pragma unroll
            for (int j = 0; j < 8; ++j) {
                const int kk = ks * 32 + q * 8 + j;
                const int h  = hw * 32 + ht * 16 + n;
                wfz[ks][ht][j] = f2bf_rne(wz1[kk * HH + h]);
                wfh[ks][ht][j] = f2bf_rne(wh1[kk * HH + h]);
            }
        }
    }

    float carry0 = 0.0f;
    float carry1[2] = {0.0f, 0.0f};    // per ht (h = hw*32 + ht*16 + n)
    f32x4 ga[2], gb[2];                // layer-1 gates (a,b), chunk-persistent
    float Aqe[2], Bqe[2];              // exclusive-q transforms, chunk-persistent
    float pvo[4] = {0, 0, 0, 0};       // hw0's deferred projection partials
    float lsum = 0.0f, lsum2 = 0.0f;
    float* outp = out + (pm ? 1 : 0);
    const int t0 = tw * 16;
    const int col0 = hidx ^ (seg << 2);          // s_h col swizzle (write side)
    const int sswz = (tw * 2 + (n >> 3)) << 2;   // read-side un-swizzle (= row>>3 << 2)

    // G2: deferred combine of chunk cm-1 (hw1's partial arrived via s_o, synced),
    // then apply layer-1 scan for chunk cm + half projection.
    auto g2_step = [&](int cm) {
        if (cm > 0 && hw == 0 && n == 15) {
            #pragma unroll
            for (int r = 0; r < 4; ++r) {
                const float v = pvo[r] + s_o[(cm - 1) & 1][tw][q * 4 + r] + bo;
                outp[((size_t)b * LL + (cm - 1) * TT + t0 + q * 4 + r) * 2] = v;
                lsum += v;
                lsum2 = fmaf(v, v, lsum2);
            }
        }
        const int buf = cm & 1;
        float Acm[2] = {1, 1}, Bcm[2] = {0, 0};
        float Ap[2], Bp[2];
        #pragma unroll
        for (int w = 0; w < 4; ++w) {
            #pragma unroll
            for (int ht = 0; ht < 2; ++ht) {
                if (w == tw) { Ap[ht] = Acm[ht]; Bp[ht] = Bcm[ht]; }
                const float2 ab = s_w[buf][hw][w][ht * 16 + n];
                Bcm[ht] = fmaf(ab.x, Bcm[ht], ab.y);
                Acm[ht] *= ab.x;
            }
        }
        float vo[4] = {0, 0, 0, 0};
        #pragma unroll
        for (int ht = 0; ht < 2; ++ht) {
            float cc = fmaf(Aqe[ht], fmaf(Ap[ht], carry1[ht], Bp[ht]), Bqe[ht]);
            #pragma unroll
            for (int r = 0; r < 4; ++r) {
                cc = fmaf(ga[ht][r], cc, gb[ht][r]);
                vo[r] = fmaf(cc, rwo4[ht], vo[r]);
            }
            carry1[ht] = fmaf(Acm[ht], carry1[ht], Bcm[ht]);
        }
        // shift-reduce over n (16-lane rows): lane n==15 gets the half-sum
        #pragma unroll
        for (int r = 0; r < 4; ++r) {
            vo[r] += rshr<1>(vo[r]);
            vo[r] += rshr<2>(vo[r]);
            vo[r] += rshr<4>(vo[r]);
            vo[r] += rshr<8>(vo[r]);
        }
        if (n == 15) {
            if (hw) {
                #pragma unroll
                for (int r = 0; r < 4; ++r) s_o[buf][tw][q * 4 + r] = vo[r];
            } else {
                #pragma unroll
                for (int r = 0; r < 4; ++r) pvo[r] = vo[r];
            }
        }
    };

    __syncthreads();   // s_xb staged

    // ---- prologue: P1(0) -> s_h buf 0 ----
    p1_scan(bw, 0, a0v, b0v, a1v, b1v, seg, col0, lane7, carry0, s_h);
    __syncthreads();

    for (int c = 0; c < NCH; ++c) {
        const int cp1 = c + 1;

        // ---- G2(c-1): uses previous chunk's gates (still in registers) ----
        if (c > 0) g2_step(c - 1);

        // ---- G1(c): MFMA + gates + per-wave scan transforms (this h-half) ----
        {
            #pragma unroll
            for (int ht = 0; ht < 2; ++ht) {
                ga[ht] = (f32x4){rbz1[ht], rbz1[ht], rbz1[ht], rbz1[ht]};
                gb[ht] = (f32x4){rbh1[ht], rbh1[ht], rbh1[ht], rbh1[ht]};
            }
            const float* shR = s_h + (c & 1) * (TT * SS);
            #pragma unroll
            for (int ks = 0; ks < 2; ++ks) {
                const int base = ks * 32 + q * 8;
                const float* rowp = &shR[(t0 + n) * SS];
                const float4 av0 = *(const float4*)(rowp + (base ^ sswz));
                const float4 av1 = *(const float4*)(rowp + ((base + 4) ^ sswz));
                float af[8] = {av0.x, av0.y, av0.z, av0.w, av1.x, av1.y, av1.z, av1.w};
                // hi16 pack via v_perm; exact remainder -> lo bf16
                union { bf16x8 v; unsigned d[4]; } ahi, alo;
                float rem[8];
                #pragma unroll
                for (int j = 0; j < 8; ++j) {
                    union { float f; unsigned u; } uf; uf.f = af[j];
                    union { unsigned u; float f; } hf; hf.u = uf.u & 0xffff0000u;
                    rem[j] = af[j] - hf.f;                     // exact
                }
                #pragma unroll
                for (int k = 0; k < 4; ++k) {
                    ahi.d[k] = perm_hi16(af[2 * k + 1], af[2 * k]);
                    alo.d[k] = perm_hi16(rem[2 * k + 1], rem[2 * k]);
                }
                #pragma unroll
                for (int ht = 0; ht < 2; ++ht) {
                    ga[ht] = __builtin_amdgcn_mfma_f32_16x16x32_bf16(ahi.v, wfz[ks][ht], ga[ht], 0, 0, 0);
                    ga[ht] = __builtin_amdgcn_mfma_f32_16x16x32_bf16(alo.v, wfz[ks][ht], ga[ht], 0, 0, 0);
                    gb[ht] = __builtin_amdgcn_mfma_f32_16x16x32_bf16(ahi.v, wfh[ks][ht], gb[ht], 0, 0, 0);
                    gb[ht] = __builtin_amdgcn_mfma_f32_16x16x32_bf16(alo.v, wfh[ks][ht], gb[ht], 0, 0, 0);
                }
            }
            // gates in place: a = 1-sigmoid(v) = rcp(1+exp(v)); b = htl - a*htl
            #pragma unroll
            for (int ht = 0; ht < 2; ++ht) {
                #pragma unroll
                for (int r = 0; r < 4; ++r) {
                    const float v   = ga[ht][r];
                    const float a   = rcp_(1.0f + __expf(v));
                    const float htl = gb[ht][r];
                    ga[ht][r] = a;
                    gb[ht][r] = fmaf(-a, htl, htl);
                }
            }
            // compose own 4 r-steps per ht
            float Aq[2], Bq[2];
            #pragma unroll
            for (int ht = 0; ht < 2; ++ht) {
                float A = 1.0f, B = 0.0f;
                #pragma unroll
                for (int r = 0; r < 4; ++r) {
                    B = fmaf(ga[ht][r], B, gb[ht][r]);
                    A = A * ga[ht][r];
                }
                Aq[ht] = A; Bq[ht] = B;
            }
            // inclusive Hillis-Steele over q (strides 16, 32 lanes)
            #pragma unroll
            for (int ht = 0; ht < 2; ++ht) {
                const float Au = __shfl_up(Aq[ht], 16), Bu = __shfl_up(Bq[ht], 16);
                if (q >= 1) { const float Ac = Aq[ht]; Aq[ht] = Ac * Au; Bq[ht] = fmaf(Ac, Bu, Bq[ht]); }
            }
            #pragma unroll
            for (int ht = 0; ht < 2; ++ht) {
                const float Au = __shfl_up(Aq[ht], 32), Bu = __shfl_up(Bq[ht], 32);
                if (q >= 2) { const float Ac = Aq[ht]; Aq[ht] = Ac * Au; Bq[ht] = fmaf(Ac, Bu, Bq[ht]); }
            }
            // exclusive-q transforms (persist to G2)
            #pragma unroll
            for (int ht = 0; ht < 2; ++ht) {
                const float Ae = __shfl_up(Aq[ht], 16), Be = __shfl_up(Bq[ht], 16);
                Aqe[ht] = (q == 0) ? 1.0f : Ae;
                Bqe[ht] = (q == 0) ? 0.0f : Be;
            }
            // q==3 lanes publish the wave-block inclusive transform
            if (q == 3) {
                #pragma unroll
                for (int ht = 0; ht < 2; ++ht)
                    s_w[c & 1][hw][tw][ht * 16 + n] = make_float2(Aq[ht], Bq[ht]);
            }
        }

        // ---- P1(c+1) -> other s_h buffer (reads bit-packed x) ----
        if (cp1 < NCH)
            p1_scan(bw, cp1, a0v, b0v, a1v, b1v, seg, col0, lane7, carry0,
                    s_h + (cp1 & 1) * (TT * SS));

        __syncthreads();
    }

    // ---- G2 for the last chunk, then final deferred combine ----
    g2_step(NCH - 1);
    __syncthreads();
    if (hw == 0 && n == 15) {
        #pragma unroll
        for (int r = 0; r < 4; ++r) {
            const float v = pvo[r] + s_o[(NCH - 1) & 1][tw][q * 4 + r] + bo;
            outp[((size_t)b * LL + (NCH - 1) * TT + t0 + q * 4 + r) * 2] = v;
            lsum += v;
            lsum2 = fmaf(v, v, lsum2);
        }
    }

    // ---- block partial (sum, sumsq) -> ws slots (plain stores) ----
    #pragma unroll
    for (int o = 32; o; o >>= 1) {
        lsum  += __shfl_down(lsum, o);
        lsum2 += __shfl_down(lsum2, o);
    }
    if (lane == 0) { s_red[tg] = lsum; s_red[8 + tg] = lsum2; }
    __syncthreads();
    if (tid == 0) {
        float s = 0.0f, s2 = 0.0f;
        #pragma unroll
        for (int i = 0; i < 8; ++i) { s += s_red[i]; s2 += s_red[8 + i]; }
        const int gb2 = b * 2 + (pm ? 1 : 0);
        ws[2 * gb2]     = s;
        ws[2 * gb2 + 1] = s2;
    }
}

// Fold the 512 block-partials (redundantly per block), normalize in-place.
__global__ void normalize_k(float* __restrict__ out, const float* __restrict__ ws)
{
    __shared__ float s_red[8];
    float s = 0.0f, s2 = 0.0f;
    for (int i = threadIdx.x; i < 2 * BB; i += 256) {
        s  += ws[2 * i];
        s2 += ws[2 * i + 1];
    }
    #pragma unroll
    for (int o = 32; o; o >>= 1) {
        s  += __shfl_down(s, o);
        s2 += __shfl_down(s2, o);
    }
    const int wid = threadIdx.x >> 6;
    if ((threadIdx.x & 63) == 0) { s_red[wid] = s; s_red[4 + wid] = s2; }
    __syncthreads();
    const float tot  = s_red[0] + s_red[1] + s_red[2] + s_red[3];
    const float tot2 = s_red[4] + s_red[5] + s_red[6] + s_red[7];
    const float N    = (float)NTOT;
    const float mean = tot / N;
    const float var  = (tot2 - N * mean * mean) / (N - 1.0f);
    const float inv  = rsqrtf(var);

    const int i = blockIdx.x * blockDim.x + threadIdx.x;   // exactly NTOT/4 threads
    float4* o4 = (float4*)out;
    float4 v = o4[i];
    v.x = (v.x - mean) * inv;
    v.y = (v.y - mean) * inv;
    v.z = (v.z - mean) * inv;
    v.w = (v.w - mean) * inv;
    o4[i] = v;
}

extern "C" void kernel_launch(void* const* d_in, const int* in_sizes, int n_in,
                              void* d_out, int out_size, void* d_ws, size_t ws_size,
                              hipStream_t stream)
{
    (void)in_sizes; (void)n_in; (void)out_size; (void)ws_size;
    const float* x = (const float*)d_in[0];
    const int*   p = (const int*)d_in[1];
    float* out = (float*)d_out;
    float* ws  = (float*)d_ws;

    dim3 grid(BB, 2);
    gru_fused<<<grid, 512, 0, stream>>>(
        x, p,
        (const float*)d_in[2],  (const float*)d_in[3],
        (const float*)d_in[4],  (const float*)d_in[5],
        (const float*)d_in[6],  (const float*)d_in[7],
        (const float*)d_in[8],  (const float*)d_in[9],
        (const float*)d_in[10], (const float*)d_in[11],
        (const float*)d_in[12], (const float*)d_in[13],
        (const float*)d_in[14], (const float*)d_in[15],
        (const float*)d_in[16], (const float*)d_in[17],
        (const float*)d_in[18], (const float*)d_in[19],
        (const float*)d_in[20], (const float*)d_in[21],
        out, ws);

    normalize_k<<<NTOT / 4 / 256, 256, 0, stream>>>(out, ws);
}